// Round 1
// baseline (332.027 us; speedup 1.0000x reference)
//
#include <hip/hip_runtime.h>
#include <hip/hip_bf16.h>

// Sizes for this problem
#define T_SEQ 4096
#define C_DIM 1024
#define NH    16
#define HD    64
#define C3    3072

typedef __attribute__((ext_vector_type(8))) short short8;
typedef __attribute__((ext_vector_type(4))) float f32x4;

__device__ __forceinline__ short f2bf(float f) {
  union { float f; unsigned u; } v; v.f = f;
  unsigned r = v.u + 0x7FFFu + ((v.u >> 16) & 1u);   // round-to-nearest-even
  return (short)(r >> 16);
}

__device__ __forceinline__ void gld_lds16(const void* g, void* l) {
  __builtin_amdgcn_global_load_lds(
      (const __attribute__((address_space(1))) unsigned int*)g,
      (__attribute__((address_space(3))) unsigned int*)l, 16, 0, 0);
}

// ---------------- fp32 -> bf16 convert (x) ----------------
__global__ __launch_bounds__(256) void conv_bf16_kernel(const float* __restrict__ in,
                                                        short* __restrict__ out) {
  const size_t i = ((size_t)blockIdx.x * 256 + threadIdx.x) * 8;
  float4 v0 = *(const float4*)(in + i);
  float4 v1 = *(const float4*)(in + i + 4);
  short8 o;
  o[0] = f2bf(v0.x); o[1] = f2bf(v0.y); o[2] = f2bf(v0.z); o[3] = f2bf(v0.w);
  o[4] = f2bf(v1.x); o[5] = f2bf(v1.y); o[6] = f2bf(v1.z); o[7] = f2bf(v1.w);
  *(short8*)(out + i) = o;
}

// ---------------- fp32 [K][N] -> bf16 [N][K] transpose-convert ----------------
__global__ void trans_conv_kernel(const float* __restrict__ in, short* __restrict__ out,
                                  int K, int N) {
  __shared__ float t[32][33];
  const int n0 = blockIdx.x * 32, k0 = blockIdx.y * 32;
  const int tx = threadIdx.x, ty = threadIdx.y;
  for (int i = ty; i < 32; i += 8) t[i][tx] = in[(size_t)(k0 + i) * N + n0 + tx];
  __syncthreads();
  for (int i = ty; i < 32; i += 8) out[(size_t)(n0 + i) * K + k0 + tx] = f2bf(t[tx][i]);
}

// ---------------- bf16 GEMM: C[M,N] = A[M,K] * BT[N,K]^T ----------------
__device__ __forceinline__ void store_out(short* C, size_t idx, float v) { C[idx] = f2bf(v); }
__device__ __forceinline__ void store_out(float* C, size_t idx, float v) { C[idx] = v; }

template <typename OutT>
__global__ __launch_bounds__(256) void gemm_bt_kernel(const short* __restrict__ A,
                                                      const short* __restrict__ BT,
                                                      OutT* __restrict__ C,
                                                      int M, int N, int K) {
  __shared__ __align__(16) short As[128 * 32];
  __shared__ __align__(16) short Bs[128 * 32];
  const int tid = threadIdx.x;
  const int wid = tid >> 6;
  const int lane = tid & 63;
  const int l15 = lane & 15;
  const int l4 = lane >> 4;
  const int wr = wid >> 1;
  const int wc = wid & 1;
  const int bm = blockIdx.y * 128;
  const int bn = blockIdx.x * 128;

  f32x4 acc[4][4];
#pragma unroll
  for (int m = 0; m < 4; ++m)
#pragma unroll
    for (int n = 0; n < 4; ++n) acc[m][n] = (f32x4){0.f, 0.f, 0.f, 0.f};

  const int ebase = wid * 1024;              // 1024 bf16 elements per wave (2 x 512)
  const int e0 = ebase + lane * 8;
  const int r0 = e0 >> 5, c0 = e0 & 31;
  const int r1 = r0 + 16;                    // e0 + 512

  for (int k0 = 0; k0 < K; k0 += 32) {
    __syncthreads();
    gld_lds16(A + (size_t)(bm + r0) * K + k0 + c0, As + ebase);
    gld_lds16(A + (size_t)(bm + r1) * K + k0 + c0, As + ebase + 512);
    gld_lds16(BT + (size_t)(bn + r0) * K + k0 + c0, Bs + ebase);
    gld_lds16(BT + (size_t)(bn + r1) * K + k0 + c0, Bs + ebase + 512);
    __syncthreads();

    short8 a[4], b[4];
#pragma unroll
    for (int m = 0; m < 4; ++m)
      a[m] = *(const short8*)&As[(wr * 64 + m * 16 + l15) * 32 + l4 * 8];
#pragma unroll
    for (int n = 0; n < 4; ++n)
      b[n] = *(const short8*)&Bs[(wc * 64 + n * 16 + l15) * 32 + l4 * 8];
#pragma unroll
    for (int m = 0; m < 4; ++m)
#pragma unroll
      for (int n = 0; n < 4; ++n)
        acc[m][n] = __builtin_amdgcn_mfma_f32_16x16x32_bf16(a[m], b[n], acc[m][n], 0, 0, 0);
  }

#pragma unroll
  for (int m = 0; m < 4; ++m) {
    const int row0 = bm + wr * 64 + m * 16 + l4 * 4;
#pragma unroll
    for (int n = 0; n < 4; ++n) {
      const int col = bn + wc * 64 + n * 16 + l15;
#pragma unroll
      for (int r = 0; r < 4; ++r)
        store_out(C, (size_t)(row0 + r) * N + col, acc[m][n][r]);
    }
  }
}

// ---------------- repack V: qkv[t][2048 + h*64 + d] -> vT[h][d][t] ----------------
__global__ __launch_bounds__(256) void repack_v_kernel(const short* __restrict__ qkv,
                                                       short* __restrict__ vT) {
  const int h = blockIdx.x >> 6;
  const int t0 = (blockIdx.x & 63) << 6;
  __shared__ __align__(16) short tile[64][72];
  const int t = threadIdx.x;
  const int r = t >> 3, c = (t & 7) << 3;
#pragma unroll
  for (int i = 0; i < 2; ++i) {
    const int rr = r + i * 32;
    *(short8*)&tile[rr][c] =
        *(const short8*)&qkv[(size_t)(t0 + rr) * C3 + 2048 + h * 64 + c];
  }
  __syncthreads();
  const int d = t >> 3, tt = (t & 7) << 3;
#pragma unroll
  for (int i = 0; i < 2; ++i) {
    const int dd = d + i * 32;
    short8 v;
#pragma unroll
    for (int j = 0; j < 8; ++j) v[j] = tile[tt + j][dd];
    *(short8*)&vT[(size_t)(h * 64 + dd) * T_SEQ + t0 + tt] = v;
  }
}

// ---------------- flash attention ----------------
// grid: NH * (T/64) blocks, 256 threads (4 waves x 16 q-rows).
__global__ __launch_bounds__(256) void attn_kernel(const short* __restrict__ qkv,
                                                   const short* __restrict__ vT,
                                                   short* __restrict__ y) {
  const int h = blockIdx.x >> 6;
  const int q0 = (blockIdx.x & 63) << 6;
  const int tid = threadIdx.x;
  const int w = tid >> 6, lane = tid & 63, l15 = lane & 15, l4 = lane >> 4;
  __shared__ __align__(16) short Ks[64][72];
  __shared__ __align__(16) short Vs[64][72];
  __shared__ __align__(16) short Ps[4][16][72];

  // Q fragments live in registers for the whole kernel
  short8 qa0, qa1;
  {
    const short* qp = qkv + (size_t)(q0 + w * 16 + l15) * C3 + h * 64 + l4 * 8;
    qa0 = *(const short8*)qp;
    qa1 = *(const short8*)(qp + 32);
  }
  f32x4 oacc[4];
#pragma unroll
  for (int d = 0; d < 4; ++d) oacc[d] = (f32x4){0.f, 0.f, 0.f, 0.f};
  float m_r[4] = {-INFINITY, -INFINITY, -INFINITY, -INFINITY};
  float l_r[4] = {0.f, 0.f, 0.f, 0.f};
  const float SCL = 0.125f * 1.44269504f;  // 1/sqrt(64) * log2(e); softmax via exp2

  for (int kv0 = 0; kv0 < T_SEQ; kv0 += 64) {
    __syncthreads();
    {  // stage K tile [64 kv][64 d] and V^T tile [64 d][64 kv]
      const int r = tid >> 3, c = (tid & 7) << 3;
      const short* kp = qkv + (size_t)(kv0 + r) * C3 + 1024 + h * 64 + c;
      *(short8*)&Ks[r][c] = *(const short8*)kp;
      *(short8*)&Ks[r + 32][c] = *(const short8*)(kp + (size_t)32 * C3);
      const short* vp = vT + (size_t)(h * 64 + r) * T_SEQ + kv0 + c;
      *(short8*)&Vs[r][c] = *(const short8*)vp;
      *(short8*)&Vs[r + 32][c] = *(const short8*)(vp + (size_t)32 * T_SEQ);
    }
    __syncthreads();

    // S = Q K^T : per wave 16 q-rows x 64 kv-cols
    f32x4 sacc[4];
#pragma unroll
    for (int n = 0; n < 4; ++n) {
      f32x4 z = (f32x4){0.f, 0.f, 0.f, 0.f};
      short8 b0 = *(const short8*)&Ks[n * 16 + l15][l4 * 8];
      short8 b1 = *(const short8*)&Ks[n * 16 + l15][32 + l4 * 8];
      z = __builtin_amdgcn_mfma_f32_16x16x32_bf16(qa0, b0, z, 0, 0, 0);
      z = __builtin_amdgcn_mfma_f32_16x16x32_bf16(qa1, b1, z, 0, 0, 0);
      sacc[n] = z;
    }

    // online softmax (row = l4*4 + r, cols spread over l15 and n)
    float t[4][4];
#pragma unroll
    for (int n = 0; n < 4; ++n)
#pragma unroll
      for (int r = 0; r < 4; ++r) t[n][r] = sacc[n][r] * SCL;

    float tm[4];
#pragma unroll
    for (int r = 0; r < 4; ++r)
      tm[r] = fmaxf(fmaxf(t[0][r], t[1][r]), fmaxf(t[2][r], t[3][r]));
#pragma unroll
    for (int mk = 1; mk <= 8; mk <<= 1)
#pragma unroll
      for (int r = 0; r < 4; ++r) tm[r] = fmaxf(tm[r], __shfl_xor(tm[r], mk, 64));

    float al[4];
#pragma unroll
    for (int r = 0; r < 4; ++r) {
      const float mn = fmaxf(m_r[r], tm[r]);
      al[r] = exp2f(m_r[r] - mn);
      m_r[r] = mn;
    }
    float pv[4][4];
#pragma unroll
    for (int n = 0; n < 4; ++n)
#pragma unroll
      for (int r = 0; r < 4; ++r) pv[n][r] = exp2f(t[n][r] - m_r[r]);

    float ps[4];
#pragma unroll
    for (int r = 0; r < 4; ++r) ps[r] = (pv[0][r] + pv[1][r]) + (pv[2][r] + pv[3][r]);
#pragma unroll
    for (int mk = 1; mk <= 8; mk <<= 1)
#pragma unroll
      for (int r = 0; r < 4; ++r) ps[r] += __shfl_xor(ps[r], mk, 64);

#pragma unroll
    for (int r = 0; r < 4; ++r) l_r[r] = l_r[r] * al[r] + ps[r];
#pragma unroll
    for (int d = 0; d < 4; ++d)
#pragma unroll
      for (int r = 0; r < 4; ++r) oacc[d][r] *= al[r];

    // P: accumulator layout -> A-fragment layout via per-wave LDS
#pragma unroll
    for (int n = 0; n < 4; ++n)
#pragma unroll
      for (int r = 0; r < 4; ++r) Ps[w][l4 * 4 + r][n * 16 + l15] = f2bf(pv[n][r]);

    short8 pa0 = *(const short8*)&Ps[w][l15][l4 * 8];
    short8 pa1 = *(const short8*)&Ps[w][l15][32 + l4 * 8];
#pragma unroll
    for (int d = 0; d < 4; ++d) {
      short8 v0 = *(const short8*)&Vs[d * 16 + l15][l4 * 8];
      short8 v1 = *(const short8*)&Vs[d * 16 + l15][32 + l4 * 8];
      oacc[d] = __builtin_amdgcn_mfma_f32_16x16x32_bf16(pa0, v0, oacc[d], 0, 0, 0);
      oacc[d] = __builtin_amdgcn_mfma_f32_16x16x32_bf16(pa1, v1, oacc[d], 0, 0, 0);
    }
  }

  // epilogue: y[t][h*64+d] = O / l
#pragma unroll
  for (int d = 0; d < 4; ++d)
#pragma unroll
    for (int r = 0; r < 4; ++r) {
      const float o = oacc[d][r] / l_r[r];
      y[(size_t)(q0 + w * 16 + l4 * 4 + r) * C_DIM + h * 64 + d * 16 + l15] = f2bf(o);
    }
}

extern "C" void kernel_launch(void* const* d_in, const int* in_sizes, int n_in,
                              void* d_out, int out_size, void* d_ws, size_t ws_size,
                              hipStream_t stream) {
  const float* x = (const float*)d_in[0];       // [T, C]
  const float* w_qkv = (const float*)d_in[1];   // [C, 3C]
  const float* w_out = (const float*)d_in[2];   // [C, C]
  float* out = (float*)d_out;                   // [T, C] fp32

  char* ws = (char*)d_ws;
  short* xb = (short*)ws;            ws += (size_t)T_SEQ * C_DIM * 2;       // 8 MB
  short* wqT = (short*)ws;           ws += (size_t)C3 * C_DIM * 2;          // 6 MB
  short* woT = (short*)ws;           ws += (size_t)C_DIM * C_DIM * 2;       // 2 MB
  short* qkv = (short*)ws;           ws += (size_t)T_SEQ * C3 * 2;          // 24 MB
  short* vT = (short*)ws;            ws += (size_t)NH * T_SEQ * HD * 2;     // 8 MB
  short* y = (short*)ws;             ws += (size_t)T_SEQ * C_DIM * 2;       // 8 MB

  // 1. convert inputs to bf16 (weights transposed to [N][K])
  conv_bf16_kernel<<<(T_SEQ * C_DIM) / (256 * 8), 256, 0, stream>>>(x, xb);
  trans_conv_kernel<<<dim3(C3 / 32, C_DIM / 32), dim3(32, 8), 0, stream>>>(w_qkv, wqT, C_DIM, C3);
  trans_conv_kernel<<<dim3(C_DIM / 32, C_DIM / 32), dim3(32, 8), 0, stream>>>(w_out, woT, C_DIM, C_DIM);

  // 2. qkv = x @ w_qkv  (bf16 out)
  gemm_bt_kernel<short><<<dim3(C3 / 128, T_SEQ / 128), 256, 0, stream>>>(xb, wqT, qkv,
                                                                         T_SEQ, C3, C_DIM);
  // 3. repack V -> V^T per head
  repack_v_kernel<<<NH * (T_SEQ / 64), 256, 0, stream>>>(qkv, vT);

  // 4. flash attention -> y [T, C] bf16
  attn_kernel<<<NH * (T_SEQ / 64), 256, 0, stream>>>(qkv, vT, y);

  // 5. out = y @ w_out  (fp32 out)
  gemm_bt_kernel<float><<<dim3(C_DIM / 128, T_SEQ / 128), 256, 0, stream>>>(y, woT, out,
                                                                            T_SEQ, C_DIM, C_DIM);
}

// Round 2
// 251.471 us; speedup vs baseline: 1.3203x; 1.3203x over previous
//
#include <hip/hip_runtime.h>
#include <hip/hip_bf16.h>

// Sizes for this problem
#define T_SEQ 4096
#define C_DIM 1024
#define NH    16
#define HD    64
#define C3    3072

typedef __attribute__((ext_vector_type(8))) short short8;
typedef __attribute__((ext_vector_type(4))) short short4v;
typedef __attribute__((ext_vector_type(4))) float f32x4;
typedef __attribute__((ext_vector_type(2))) unsigned uint2v;

__device__ __forceinline__ short f2bf(float f) {
  union { float f; unsigned u; } v; v.f = f;
  unsigned r = v.u + 0x7FFFu + ((v.u >> 16) & 1u);   // round-to-nearest-even
  return (short)(r >> 16);
}

__device__ __forceinline__ unsigned cvt_pk_bf16(float lo, float hi) {
  unsigned r;
  asm volatile("v_cvt_pk_bf16_f32 %0, %1, %2" : "=v"(r) : "v"(lo), "v"(hi));
  return r;
}

__device__ __forceinline__ void gld_lds16(const void* g, void* l) {
  __builtin_amdgcn_global_load_lds(
      (const __attribute__((address_space(1))) unsigned int*)g,
      (__attribute__((address_space(3))) unsigned int*)l, 16, 0, 0);
}

// ---------------- fp32 -> bf16 convert (x) ----------------
__global__ __launch_bounds__(256) void conv_bf16_kernel(const float* __restrict__ in,
                                                        short* __restrict__ out) {
  const size_t i = ((size_t)blockIdx.x * 256 + threadIdx.x) * 8;
  float4 v0 = *(const float4*)(in + i);
  float4 v1 = *(const float4*)(in + i + 4);
  short8 o;
  o[0] = f2bf(v0.x); o[1] = f2bf(v0.y); o[2] = f2bf(v0.z); o[3] = f2bf(v0.w);
  o[4] = f2bf(v1.x); o[5] = f2bf(v1.y); o[6] = f2bf(v1.z); o[7] = f2bf(v1.w);
  *(short8*)(out + i) = o;
}

// ---------------- fp32 [K][N] -> bf16 [N][K] transpose-convert ----------------
__global__ void trans_conv_kernel(const float* __restrict__ in, short* __restrict__ out,
                                  int K, int N) {
  __shared__ float t[32][33];
  const int n0 = blockIdx.x * 32, k0 = blockIdx.y * 32;
  const int tx = threadIdx.x, ty = threadIdx.y;
  for (int i = ty; i < 32; i += 8) t[i][tx] = in[(size_t)(k0 + i) * N + n0 + tx];
  __syncthreads();
  for (int i = ty; i < 32; i += 8) out[(size_t)(n0 + i) * K + k0 + tx] = f2bf(t[tx][i]);
}

// ---------------- bf16 GEMM: C[M,N] = A[M,K] * BT[N,K]^T ----------------
__device__ __forceinline__ void store_out(short* C, size_t idx, float v) { C[idx] = f2bf(v); }
__device__ __forceinline__ void store_out(float* C, size_t idx, float v) { C[idx] = v; }

template <typename OutT>
__global__ __launch_bounds__(256) void gemm_bt_kernel(const short* __restrict__ A,
                                                      const short* __restrict__ BT,
                                                      OutT* __restrict__ C,
                                                      int M, int N, int K) {
  __shared__ __align__(16) short As[128 * 32];
  __shared__ __align__(16) short Bs[128 * 32];
  const int tid = threadIdx.x;
  const int wid = tid >> 6;
  const int lane = tid & 63;
  const int l15 = lane & 15;
  const int l4 = lane >> 4;
  const int wr = wid >> 1;
  const int wc = wid & 1;
  const int bm = blockIdx.y * 128;
  const int bn = blockIdx.x * 128;

  f32x4 acc[4][4];
#pragma unroll
  for (int m = 0; m < 4; ++m)
#pragma unroll
    for (int n = 0; n < 4; ++n) acc[m][n] = (f32x4){0.f, 0.f, 0.f, 0.f};

  const int ebase = wid * 1024;              // 1024 bf16 elements per wave (2 x 512)
  const int e0 = ebase + lane * 8;
  const int r0 = e0 >> 5, c0 = e0 & 31;
  const int r1 = r0 + 16;                    // e0 + 512

  for (int k0 = 0; k0 < K; k0 += 32) {
    __syncthreads();
    gld_lds16(A + (size_t)(bm + r0) * K + k0 + c0, As + ebase);
    gld_lds16(A + (size_t)(bm + r1) * K + k0 + c0, As + ebase + 512);
    gld_lds16(BT + (size_t)(bn + r0) * K + k0 + c0, Bs + ebase);
    gld_lds16(BT + (size_t)(bn + r1) * K + k0 + c0, Bs + ebase + 512);
    __syncthreads();

    short8 a[4], b[4];
#pragma unroll
    for (int m = 0; m < 4; ++m)
      a[m] = *(const short8*)&As[(wr * 64 + m * 16 + l15) * 32 + l4 * 8];
#pragma unroll
    for (int n = 0; n < 4; ++n)
      b[n] = *(const short8*)&Bs[(wc * 64 + n * 16 + l15) * 32 + l4 * 8];
#pragma unroll
    for (int m = 0; m < 4; ++m)
#pragma unroll
      for (int n = 0; n < 4; ++n)
        acc[m][n] = __builtin_amdgcn_mfma_f32_16x16x32_bf16(a[m], b[n], acc[m][n], 0, 0, 0);
  }

#pragma unroll
  for (int m = 0; m < 4; ++m) {
    const int row0 = bm + wr * 64 + m * 16 + l4 * 4;
#pragma unroll
    for (int n = 0; n < 4; ++n) {
      const int col = bn + wc * 64 + n * 16 + l15;
#pragma unroll
      for (int r = 0; r < 4; ++r)
        store_out(C, (size_t)(row0 + r) * N + col, acc[m][n][r]);
    }
  }
}

// ---------------- repack V: qkv[t][2048 + h*64 + d] -> vT[h][d][t] ----------------
__global__ __launch_bounds__(256) void repack_v_kernel(const short* __restrict__ qkv,
                                                       short* __restrict__ vT) {
  const int h = blockIdx.x >> 6;
  const int t0 = (blockIdx.x & 63) << 6;
  __shared__ __align__(16) short tile[64][72];
  const int t = threadIdx.x;
  const int r = t >> 3, c = (t & 7) << 3;
#pragma unroll
  for (int i = 0; i < 2; ++i) {
    const int rr = r + i * 32;
    *(short8*)&tile[rr][c] =
        *(const short8*)&qkv[(size_t)(t0 + rr) * C3 + 2048 + h * 64 + c];
  }
  __syncthreads();
  const int d = t >> 3, tt = (t & 7) << 3;
#pragma unroll
  for (int i = 0; i < 2; ++i) {
    const int dd = d + i * 32;
    short8 v;
#pragma unroll
    for (int j = 0; j < 8; ++j) v[j] = tile[tt + j][dd];
    *(short8*)&vT[(size_t)(h * 64 + dd) * T_SEQ + t0 + tt] = v;
  }
}

// ---------------- flash attention (swapped-QK^T, in-register softmax) ----------------
// grid: NH * (T/64) blocks, 256 threads (4 waves x 16 q-rows).
// Per lane: q = l15 (one q-row); S^T accumulator holds kv = 16n + 4*l4 + r.
__global__ __launch_bounds__(256) void attn_kernel(const short* __restrict__ qkv,
                                                   const short* __restrict__ vT,
                                                   short* __restrict__ y) {
  const int h = blockIdx.x >> 6;
  const int q0 = (blockIdx.x & 63) << 6;
  const int tid = threadIdx.x;
  const int w = tid >> 6, lane = tid & 63, l15 = lane & 15, l4 = lane >> 4;
  __shared__ __align__(16) short Ks[64][72];
  __shared__ __align__(16) short Vs[64][72];
  __shared__ __align__(16) unsigned Pw[4][16][36];   // per-wave P, packed bf16 pairs

  // Q fragments live in registers for the whole kernel (row=q=l15, k=d=l4*8+j)
  short8 qa0, qa1;
  {
    const short* qp = qkv + (size_t)(q0 + w * 16 + l15) * C3 + h * 64 + l4 * 8;
    qa0 = *(const short8*)qp;
    qa1 = *(const short8*)(qp + 32);
  }
  f32x4 oacc[4];  // O^T: col=q=l15, row d = dt*16 + l4*4 + r
#pragma unroll
  for (int d = 0; d < 4; ++d) oacc[d] = (f32x4){0.f, 0.f, 0.f, 0.f};
  float m_r = -INFINITY;   // running max (unscaled S domain), per q-row
  float l_r = 0.f;
  const float SCL = 0.125f * 1.44269504f;  // 1/sqrt(64) * log2(e); softmax via exp2

  for (int kv0 = 0; kv0 < T_SEQ; kv0 += 64) {
    __syncthreads();
    {  // stage K tile [64 kv][64 d] and V^T tile [64 d][64 kv]
      const int r = tid >> 3, c = (tid & 7) << 3;
      const short* kp = qkv + (size_t)(kv0 + r) * C3 + 1024 + h * 64 + c;
      *(short8*)&Ks[r][c] = *(const short8*)kp;
      *(short8*)&Ks[r + 32][c] = *(const short8*)(kp + (size_t)32 * C3);
      const short* vp = vT + (size_t)(h * 64 + r) * T_SEQ + kv0 + c;
      *(short8*)&Vs[r][c] = *(const short8*)vp;
      *(short8*)&Vs[r + 32][c] = *(const short8*)(vp + (size_t)32 * T_SEQ);
    }
    __syncthreads();

    // S^T = K Q^T : sacc[n][r] = S[q=l15][kv = 16n + 4*l4 + r]
    f32x4 sacc[4];
#pragma unroll
    for (int n = 0; n < 4; ++n) {
      f32x4 z = (f32x4){0.f, 0.f, 0.f, 0.f};
      short8 k0 = *(const short8*)&Ks[n * 16 + l15][l4 * 8];
      short8 k1 = *(const short8*)&Ks[n * 16 + l15][32 + l4 * 8];
      z = __builtin_amdgcn_mfma_f32_16x16x32_bf16(k0, qa0, z, 0, 0, 0);
      z = __builtin_amdgcn_mfma_f32_16x16x32_bf16(k1, qa1, z, 0, 0, 0);
      sacc[n] = z;
    }

    // online softmax, fully per-lane (row = q = l15)
    float tm = sacc[0][0];
#pragma unroll
    for (int n = 0; n < 4; ++n)
#pragma unroll
      for (int r = 0; r < 4; ++r) tm = fmaxf(tm, sacc[n][r]);
    tm = fmaxf(tm, __shfl_xor(tm, 16, 64));
    tm = fmaxf(tm, __shfl_xor(tm, 32, 64));

    const float mn = fmaxf(m_r, tm);
    const float al = exp2f((m_r - mn) * SCL);
    m_r = mn;
    const float msc = mn * SCL;

    float p[4][4];
#pragma unroll
    for (int n = 0; n < 4; ++n)
#pragma unroll
      for (int r = 0; r < 4; ++r) p[n][r] = exp2f(fmaf(sacc[n][r], SCL, -msc));

    float ps = 0.f;
#pragma unroll
    for (int n = 0; n < 4; ++n)
      ps += (p[n][0] + p[n][1]) + (p[n][2] + p[n][3]);
    ps += __shfl_xor(ps, 16, 64);
    ps += __shfl_xor(ps, 32, 64);
    l_r = l_r * al + ps;

#pragma unroll
    for (int d = 0; d < 4; ++d)
#pragma unroll
      for (int r = 0; r < 4; ++r) oacc[d][r] *= al;

    // P -> bf16 packed pairs -> per-wave LDS (b64 writes, 2-way = free)
#pragma unroll
    for (int n = 0; n < 4; ++n) {
      uint2v pk;
      pk[0] = cvt_pk_bf16(p[n][0], p[n][1]);
      pk[1] = cvt_pk_bf16(p[n][2], p[n][3]);
      *(uint2v*)&Pw[w][l15][8 * n + 2 * l4] = pk;   // word = kv/2, kv = 16n+4*l4
    }

    // B-fragment reads: pb_kb holds kv = kb*32 + l4*8 + j for q-col l15
    short8 pb0 = *(const short8*)&Pw[w][l15][4 * l4];
    short8 pb1 = *(const short8*)&Pw[w][l15][16 + 4 * l4];

    // O^T += V^T P^T  (A = V^T frag: row d = dt*16+l15, k = kv)
#pragma unroll
    for (int dt = 0; dt < 4; ++dt) {
      short8 v0 = *(const short8*)&Vs[dt * 16 + l15][l4 * 8];
      short8 v1 = *(const short8*)&Vs[dt * 16 + l15][32 + l4 * 8];
      oacc[dt] = __builtin_amdgcn_mfma_f32_16x16x32_bf16(v0, pb0, oacc[dt], 0, 0, 0);
      oacc[dt] = __builtin_amdgcn_mfma_f32_16x16x32_bf16(v1, pb1, oacc[dt], 0, 0, 0);
    }
  }

  // epilogue: y[q][h*64+d] = O / l, 4 consecutive d per 8B store
  const float rl = 1.0f / l_r;
  const size_t row = (size_t)(q0 + w * 16 + l15) * C_DIM + h * 64;
#pragma unroll
  for (int dt = 0; dt < 4; ++dt) {
    short4v o;
#pragma unroll
    for (int r = 0; r < 4; ++r) o[r] = f2bf(oacc[dt][r] * rl);
    *(short4v*)&y[row + dt * 16 + l4 * 4] = o;
  }
}

extern "C" void kernel_launch(void* const* d_in, const int* in_sizes, int n_in,
                              void* d_out, int out_size, void* d_ws, size_t ws_size,
                              hipStream_t stream) {
  const float* x = (const float*)d_in[0];       // [T, C]
  const float* w_qkv = (const float*)d_in[1];   // [C, 3C]
  const float* w_out = (const float*)d_in[2];   // [C, C]
  float* out = (float*)d_out;                   // [T, C] fp32

  char* ws = (char*)d_ws;
  short* xb = (short*)ws;            ws += (size_t)T_SEQ * C_DIM * 2;       // 8 MB
  short* wqT = (short*)ws;           ws += (size_t)C3 * C_DIM * 2;          // 6 MB
  short* woT = (short*)ws;           ws += (size_t)C_DIM * C_DIM * 2;       // 2 MB
  short* qkv = (short*)ws;           ws += (size_t)T_SEQ * C3 * 2;          // 24 MB
  short* vT = (short*)ws;            ws += (size_t)NH * T_SEQ * HD * 2;     // 8 MB
  short* y = (short*)ws;             ws += (size_t)T_SEQ * C_DIM * 2;       // 8 MB

  // 1. convert inputs to bf16 (weights transposed to [N][K])
  conv_bf16_kernel<<<(T_SEQ * C_DIM) / (256 * 8), 256, 0, stream>>>(x, xb);
  trans_conv_kernel<<<dim3(C3 / 32, C_DIM / 32), dim3(32, 8), 0, stream>>>(w_qkv, wqT, C_DIM, C3);
  trans_conv_kernel<<<dim3(C_DIM / 32, C_DIM / 32), dim3(32, 8), 0, stream>>>(w_out, woT, C_DIM, C_DIM);

  // 2. qkv = x @ w_qkv  (bf16 out)
  gemm_bt_kernel<short><<<dim3(C3 / 128, T_SEQ / 128), 256, 0, stream>>>(xb, wqT, qkv,
                                                                         T_SEQ, C3, C_DIM);
  // 3. repack V -> V^T per head
  repack_v_kernel<<<NH * (T_SEQ / 64), 256, 0, stream>>>(qkv, vT);

  // 4. flash attention -> y [T, C] bf16
  attn_kernel<<<NH * (T_SEQ / 64), 256, 0, stream>>>(qkv, vT, y);

  // 5. out = y @ w_out  (fp32 out)
  gemm_bt_kernel<float><<<dim3(C_DIM / 128, T_SEQ / 128), 256, 0, stream>>>(y, woT, out,
                                                                            T_SEQ, C_DIM, C_DIM);
}

// Round 3
// 220.340 us; speedup vs baseline: 1.5069x; 1.1413x over previous
//
#include <hip/hip_runtime.h>
#include <hip/hip_bf16.h>

// Sizes for this problem
#define T_SEQ 4096
#define C_DIM 1024
#define NH    16
#define HD    64
#define C3    3072

typedef __attribute__((ext_vector_type(8))) short short8;
typedef __attribute__((ext_vector_type(4))) short short4v;
typedef __attribute__((ext_vector_type(4))) float f32x4;
typedef __attribute__((ext_vector_type(16))) float f32x16;

__device__ __forceinline__ short f2bf(float f) {
  union { float f; unsigned u; } v; v.f = f;
  unsigned r = v.u + 0x7FFFu + ((v.u >> 16) & 1u);   // round-to-nearest-even
  return (short)(r >> 16);
}

__device__ __forceinline__ unsigned cvt_pk_bf16(float lo, float hi) {
  unsigned r;
  asm volatile("v_cvt_pk_bf16_f32 %0, %1, %2" : "=v"(r) : "v"(lo), "v"(hi));
  return r;
}

__device__ __forceinline__ void gld_lds16(const void* g, void* l) {
  __builtin_amdgcn_global_load_lds(
      (const __attribute__((address_space(1))) unsigned int*)g,
      (__attribute__((address_space(3))) unsigned int*)l, 16, 0, 0);
}

// ---------------- fp32 -> bf16 convert (x) ----------------
__global__ __launch_bounds__(256) void conv_bf16_kernel(const float* __restrict__ in,
                                                        short* __restrict__ out) {
  const size_t i = ((size_t)blockIdx.x * 256 + threadIdx.x) * 8;
  float4 v0 = *(const float4*)(in + i);
  float4 v1 = *(const float4*)(in + i + 4);
  short8 o;
  o[0] = f2bf(v0.x); o[1] = f2bf(v0.y); o[2] = f2bf(v0.z); o[3] = f2bf(v0.w);
  o[4] = f2bf(v1.x); o[5] = f2bf(v1.y); o[6] = f2bf(v1.z); o[7] = f2bf(v1.w);
  *(short8*)(out + i) = o;
}

// ---------------- fp32 [K][N] -> bf16 [N][K] transpose-convert ----------------
__global__ void trans_conv_kernel(const float* __restrict__ in, short* __restrict__ out,
                                  int K, int N) {
  __shared__ float t[32][33];
  const int n0 = blockIdx.x * 32, k0 = blockIdx.y * 32;
  const int tx = threadIdx.x, ty = threadIdx.y;
  for (int i = ty; i < 32; i += 8) t[i][tx] = in[(size_t)(k0 + i) * N + n0 + tx];
  __syncthreads();
  for (int i = ty; i < 32; i += 8) out[(size_t)(n0 + i) * K + k0 + tx] = f2bf(t[tx][i]);
}

// ---------------- bf16 GEMM: C[M,N] = A[M,K] * BT[N,K]^T ----------------
__device__ __forceinline__ void store_out(short* C, size_t idx, float v) { C[idx] = f2bf(v); }
__device__ __forceinline__ void store_out(float* C, size_t idx, float v) { C[idx] = v; }

template <typename OutT>
__global__ __launch_bounds__(256) void gemm_bt_kernel(const short* __restrict__ A,
                                                      const short* __restrict__ BT,
                                                      OutT* __restrict__ C,
                                                      int M, int N, int K) {
  __shared__ __align__(16) short As[128 * 32];
  __shared__ __align__(16) short Bs[128 * 32];
  const int tid = threadIdx.x;
  const int wid = tid >> 6;
  const int lane = tid & 63;
  const int l15 = lane & 15;
  const int l4 = lane >> 4;
  const int wr = wid >> 1;
  const int wc = wid & 1;
  const int bm = blockIdx.y * 128;
  const int bn = blockIdx.x * 128;

  f32x4 acc[4][4];
#pragma unroll
  for (int m = 0; m < 4; ++m)
#pragma unroll
    for (int n = 0; n < 4; ++n) acc[m][n] = (f32x4){0.f, 0.f, 0.f, 0.f};

  const int ebase = wid * 1024;              // 1024 bf16 elements per wave (2 x 512)
  const int e0 = ebase + lane * 8;
  const int r0 = e0 >> 5, c0 = e0 & 31;
  const int r1 = r0 + 16;                    // e0 + 512

  for (int k0 = 0; k0 < K; k0 += 32) {
    __syncthreads();
    gld_lds16(A + (size_t)(bm + r0) * K + k0 + c0, As + ebase);
    gld_lds16(A + (size_t)(bm + r1) * K + k0 + c0, As + ebase + 512);
    gld_lds16(BT + (size_t)(bn + r0) * K + k0 + c0, Bs + ebase);
    gld_lds16(BT + (size_t)(bn + r1) * K + k0 + c0, Bs + ebase + 512);
    __syncthreads();

    short8 a[4], b[4];
#pragma unroll
    for (int m = 0; m < 4; ++m)
      a[m] = *(const short8*)&As[(wr * 64 + m * 16 + l15) * 32 + l4 * 8];
#pragma unroll
    for (int n = 0; n < 4; ++n)
      b[n] = *(const short8*)&Bs[(wc * 64 + n * 16 + l15) * 32 + l4 * 8];
#pragma unroll
    for (int m = 0; m < 4; ++m)
#pragma unroll
      for (int n = 0; n < 4; ++n)
        acc[m][n] = __builtin_amdgcn_mfma_f32_16x16x32_bf16(a[m], b[n], acc[m][n], 0, 0, 0);
  }

#pragma unroll
  for (int m = 0; m < 4; ++m) {
    const int row0 = bm + wr * 64 + m * 16 + l4 * 4;
#pragma unroll
    for (int n = 0; n < 4; ++n) {
      const int col = bn + wc * 64 + n * 16 + l15;
#pragma unroll
      for (int r = 0; r < 4; ++r)
        store_out(C, (size_t)(row0 + r) * N + col, acc[m][n][r]);
    }
  }
}

// ---------------- repack V: qkv[t][2048 + h*64 + d] -> vT[h][d][t] ----------------
__global__ __launch_bounds__(256) void repack_v_kernel(const short* __restrict__ qkv,
                                                       short* __restrict__ vT) {
  const int h = blockIdx.x >> 6;
  const int t0 = (blockIdx.x & 63) << 6;
  __shared__ __align__(16) short tile[64][72];
  const int t = threadIdx.x;
  const int r = t >> 3, c = (t & 7) << 3;
#pragma unroll
  for (int i = 0; i < 2; ++i) {
    const int rr = r + i * 32;
    *(short8*)&tile[rr][c] =
        *(const short8*)&qkv[(size_t)(t0 + rr) * C3 + 2048 + h * 64 + c];
  }
  __syncthreads();
  const int d = t >> 3, tt = (t & 7) << 3;
#pragma unroll
  for (int i = 0; i < 2; ++i) {
    const int dd = d + i * 32;
    short8 v;
#pragma unroll
    for (int j = 0; j < 8; ++j) v[j] = tile[tt + j][dd];
    *(short8*)&vT[(size_t)(h * 64 + dd) * T_SEQ + t0 + tt] = v;
  }
}

// ---------------- flash attention: 32x32 MFMA, in-register P ----------------
// 512 blocks = 16 heads x 32 q-blocks(128 q). 4 waves x 32 q-rows.
// Per lane: q = lane&31 (one q-column of S^T); 32 kv values in 2 f32x16 accs.
__global__ __launch_bounds__(256) void attn_kernel(const short* __restrict__ qkv,
                                                   const short* __restrict__ vT,
                                                   short* __restrict__ y) {
  // XCD-aware: heads {2x, 2x+1} -> XCD x (round-robin bid%8 assumption)
  const int bid = blockIdx.x;
  const int xcd = bid & 7, slot = bid >> 3;      // slot 0..63
  const int h = xcd * 2 + (slot >> 5);
  const int q0 = (slot & 31) * 128;

  const int tid = threadIdx.x;
  const int w = tid >> 6, lane = tid & 63, l31 = lane & 31, l1 = lane >> 5;

  __shared__ __align__(16) short Ks[2][64 * 64];   // [kv][d], d-swizzled
  __shared__ __align__(16) short Vs[2][64 * 64];   // [d][kv], kv-swizzled

  // Q B-fragments: col q = l31, k = d = ks*16 + l1*8 + j
  short8 qf[4];
  {
    const short* qp = qkv + (size_t)(q0 + w * 32 + l31) * C3 + h * 64 + l1 * 8;
#pragma unroll
    for (int ks = 0; ks < 4; ++ks) qf[ks] = *(const short8*)(qp + ks * 16);
  }

  f32x16 oa0, oa1;   // O^T: col q=l31, row d=(r&3)+8*(r>>2)+4*l1 (+32 for oa1)
#pragma unroll
  for (int r = 0; r < 16; ++r) { oa0[r] = 0.f; oa1[r] = 0.f; }
  float m_r = -INFINITY, l_r = 0.f;
  const float SCL = 0.125f * 1.44269504f;          // 1/sqrt(64) * log2(e)
  const float TH = 8.0f / SCL;                     // defer-max threshold (p <= 2^8)

  // staging constants: row lr0 = w*8 + (lane>>3) (+32 for i=1), swizzled col
  const int lr0 = w * 8 + (lane >> 3);
  const int csw = ((lane & 7) << 3) ^ ((lane >> 3) << 3);   // shorts
  const short* kgb = qkv + 1024 + h * 64 + csw;
  const short* vgb = vT + (size_t)(h * 64 + lr0) * T_SEQ + csw;
  const int rswz = (l31 & 7) << 3;

  auto stage = [&](int buf, int kv0) {
#pragma unroll
    for (int i = 0; i < 2; ++i) {
      gld_lds16(kgb + (size_t)(kv0 + lr0 + i * 32) * C3, &Ks[buf][i * 2048 + w * 512]);
      gld_lds16(vgb + (size_t)(i * 32) * T_SEQ + kv0, &Vs[buf][i * 2048 + w * 512]);
    }
  };

  stage(0, 0);

  for (int t = 0; t < T_SEQ / 64; ++t) {
    const int cur = t & 1;
    __syncthreads();                       // drains vmcnt(0): buf[cur] ready
    if (t < T_SEQ / 64 - 1) stage(cur ^ 1, (t + 1) * 64);

    const short* Kb = &Ks[cur][0];
    const short* Vb = &Vs[cur][0];

    // S^T = K Q^T: two 32-kv subtiles
    f32x16 s0, s1;
#pragma unroll
    for (int r = 0; r < 16; ++r) { s0[r] = 0.f; s1[r] = 0.f; }
#pragma unroll
    for (int ks = 0; ks < 4; ++ks) {
      const int c = (ks * 16 + l1 * 8) ^ rswz;
      short8 k0 = *(const short8*)&Kb[l31 * 64 + c];
      short8 k1 = *(const short8*)&Kb[(32 + l31) * 64 + c];
      s0 = __builtin_amdgcn_mfma_f32_32x32x16_bf16(k0, qf[ks], s0, 0, 0, 0);
      s1 = __builtin_amdgcn_mfma_f32_32x32x16_bf16(k1, qf[ks], s1, 0, 0, 0);
    }

    // online softmax, per-lane (col q = l31); rows split across lane ^ 32
    float tm = s0[0];
#pragma unroll
    for (int r = 1; r < 16; ++r) tm = fmaxf(tm, s0[r]);
#pragma unroll
    for (int r = 0; r < 16; ++r) tm = fmaxf(tm, s1[r]);
    tm = fmaxf(tm, __shfl_xor(tm, 32, 64));

    if (__any(tm > m_r + TH)) {            // defer-max: skip rescale on stable tiles
      const float mn = fmaxf(m_r, tm);
      const float al = exp2f((m_r - mn) * SCL);
      m_r = mn;
      l_r *= al;
#pragma unroll
      for (int r = 0; r < 16; ++r) { oa0[r] *= al; oa1[r] *= al; }
    }
    const float msc = m_r * SCL;
#pragma unroll
    for (int r = 0; r < 16; ++r) s0[r] = exp2f(fmaf(s0[r], SCL, -msc));
#pragma unroll
    for (int r = 0; r < 16; ++r) s1[r] = exp2f(fmaf(s1[r], SCL, -msc));

    float ps = 0.f;
#pragma unroll
    for (int r = 0; r < 16; ++r) ps += s0[r] + s1[r];
    ps += __shfl_xor(ps, 32, 64);
    l_r += ps;

    // P -> B-fragments in-register: cvt_pk + permlane32_swap (T12)
    // ks-th frag dwords: k pairs (l1*8+2t, +1) of kv-step ks
    unsigned pw[4][4];
#pragma unroll
    for (int half = 0; half < 2; ++half) {
      const f32x16& sv = half ? s1 : s0;
#pragma unroll
      for (int kk = 0; kk < 2; ++kk) {       // local kstep within subtile
        const int ks = half * 2 + kk;
        unsigned x0 = cvt_pk_bf16(sv[kk * 8 + 0], sv[kk * 8 + 1]);
        unsigned y0 = cvt_pk_bf16(sv[kk * 8 + 4], sv[kk * 8 + 5]);
        asm volatile("v_permlane32_swap_b32 %0, %1" : "+v"(x0), "+v"(y0));
        unsigned x1 = cvt_pk_bf16(sv[kk * 8 + 2], sv[kk * 8 + 3]);
        unsigned y1 = cvt_pk_bf16(sv[kk * 8 + 6], sv[kk * 8 + 7]);
        asm volatile("v_permlane32_swap_b32 %0, %1" : "+v"(x1), "+v"(y1));
        pw[ks][0] = x0; pw[ks][1] = x1; pw[ks][2] = y0; pw[ks][3] = y1;
      }
    }

    // O^T += V^T P^T
#pragma unroll
    for (int ks = 0; ks < 4; ++ks) {
      union { unsigned u[4]; short8 s8; } uu;
      uu.u[0] = pw[ks][0]; uu.u[1] = pw[ks][1]; uu.u[2] = pw[ks][2]; uu.u[3] = pw[ks][3];
      const int c = (ks * 16 + l1 * 8) ^ rswz;
      short8 v0 = *(const short8*)&Vb[l31 * 64 + c];
      short8 v1 = *(const short8*)&Vb[(32 + l31) * 64 + c];
      oa0 = __builtin_amdgcn_mfma_f32_32x32x16_bf16(v0, uu.s8, oa0, 0, 0, 0);
      oa1 = __builtin_amdgcn_mfma_f32_32x32x16_bf16(v1, uu.s8, oa1, 0, 0, 0);
    }
  }

  // epilogue: y[q][h*64 + d] = O/l ; d = dt*32 + 8g + 4*l1 + j
  const float rl = 1.0f / l_r;
  const size_t yb = (size_t)(q0 + w * 32 + l31) * C_DIM + h * 64;
#pragma unroll
  for (int g = 0; g < 4; ++g) {
    short4v o0, o1;
#pragma unroll
    for (int j = 0; j < 4; ++j) {
      o0[j] = f2bf(oa0[g * 4 + j] * rl);
      o1[j] = f2bf(oa1[g * 4 + j] * rl);
    }
    *(short4v*)&y[yb + g * 8 + l1 * 4] = o0;
    *(short4v*)&y[yb + 32 + g * 8 + l1 * 4] = o1;
  }
}

extern "C" void kernel_launch(void* const* d_in, const int* in_sizes, int n_in,
                              void* d_out, int out_size, void* d_ws, size_t ws_size,
                              hipStream_t stream) {
  const float* x = (const float*)d_in[0];       // [T, C]
  const float* w_qkv = (const float*)d_in[1];   // [C, 3C]
  const float* w_out = (const float*)d_in[2];   // [C, C]
  float* out = (float*)d_out;                   // [T, C] fp32

  char* ws = (char*)d_ws;
  short* xb = (short*)ws;            ws += (size_t)T_SEQ * C_DIM * 2;       // 8 MB
  short* wqT = (short*)ws;           ws += (size_t)C3 * C_DIM * 2;          // 6 MB
  short* woT = (short*)ws;           ws += (size_t)C_DIM * C_DIM * 2;       // 2 MB
  short* qkv = (short*)ws;           ws += (size_t)T_SEQ * C3 * 2;          // 24 MB
  short* vT = (short*)ws;            ws += (size_t)NH * T_SEQ * HD * 2;     // 8 MB
  short* y = (short*)ws;             ws += (size_t)T_SEQ * C_DIM * 2;       // 8 MB

  // 1. convert inputs to bf16 (weights transposed to [N][K])
  conv_bf16_kernel<<<(T_SEQ * C_DIM) / (256 * 8), 256, 0, stream>>>(x, xb);
  trans_conv_kernel<<<dim3(C3 / 32, C_DIM / 32), dim3(32, 8), 0, stream>>>(w_qkv, wqT, C_DIM, C3);
  trans_conv_kernel<<<dim3(C_DIM / 32, C_DIM / 32), dim3(32, 8), 0, stream>>>(w_out, woT, C_DIM, C_DIM);

  // 2. qkv = x @ w_qkv  (bf16 out)
  gemm_bt_kernel<short><<<dim3(C3 / 128, T_SEQ / 128), 256, 0, stream>>>(xb, wqT, qkv,
                                                                         T_SEQ, C3, C_DIM);
  // 3. repack V -> V^T per head
  repack_v_kernel<<<NH * (T_SEQ / 64), 256, 0, stream>>>(qkv, vT);

  // 4. flash attention -> y [T, C] bf16
  attn_kernel<<<512, 256, 0, stream>>>(qkv, vT, y);

  // 5. out = y @ w_out  (fp32 out)
  gemm_bt_kernel<float><<<dim3(C_DIM / 128, T_SEQ / 128), 256, 0, stream>>>(y, woT, out,
                                                                            T_SEQ, C_DIM, C_DIM);
}

// Round 4
// 208.097 us; speedup vs baseline: 1.5955x; 1.0588x over previous
//
#include <hip/hip_runtime.h>
#include <hip/hip_bf16.h>

// Sizes for this problem
#define T_SEQ 4096
#define C_DIM 1024
#define NH    16
#define HD    64
#define C3    3072

typedef __attribute__((ext_vector_type(8))) short short8;
typedef __attribute__((ext_vector_type(4))) short short4v;
typedef __attribute__((ext_vector_type(4))) float f32x4;
typedef __attribute__((ext_vector_type(16))) float f32x16;

__device__ __forceinline__ short f2bf(float f) {
  union { float f; unsigned u; } v; v.f = f;
  unsigned r = v.u + 0x7FFFu + ((v.u >> 16) & 1u);   // round-to-nearest-even
  return (short)(r >> 16);
}

__device__ __forceinline__ unsigned cvt_pk_bf16(float lo, float hi) {
  unsigned r;
  asm volatile("v_cvt_pk_bf16_f32 %0, %1, %2" : "=v"(r) : "v"(lo), "v"(hi));
  return r;
}

__device__ __forceinline__ void gld_lds16(const void* g, void* l) {
  __builtin_amdgcn_global_load_lds(
      (const __attribute__((address_space(1))) unsigned int*)g,
      (__attribute__((address_space(3))) unsigned int*)l, 16, 0, 0);
}

// ---------------- fp32 -> bf16 convert (x) ----------------
__global__ __launch_bounds__(256) void conv_bf16_kernel(const float* __restrict__ in,
                                                        short* __restrict__ out) {
  const size_t i = ((size_t)blockIdx.x * 256 + threadIdx.x) * 8;
  float4 v0 = *(const float4*)(in + i);
  float4 v1 = *(const float4*)(in + i + 4);
  short8 o;
  o[0] = f2bf(v0.x); o[1] = f2bf(v0.y); o[2] = f2bf(v0.z); o[3] = f2bf(v0.w);
  o[4] = f2bf(v1.x); o[5] = f2bf(v1.y); o[6] = f2bf(v1.z); o[7] = f2bf(v1.w);
  *(short8*)(out + i) = o;
}

// ---------------- fp32 [K][N] -> bf16 [N][K] transpose-convert ----------------
__global__ void trans_conv_kernel(const float* __restrict__ in, short* __restrict__ out,
                                  int K, int N) {
  __shared__ float t[32][33];
  const int n0 = blockIdx.x * 32, k0 = blockIdx.y * 32;
  const int tx = threadIdx.x, ty = threadIdx.y;
  for (int i = ty; i < 32; i += 8) t[i][tx] = in[(size_t)(k0 + i) * N + n0 + tx];
  __syncthreads();
  for (int i = ty; i < 32; i += 8) out[(size_t)(n0 + i) * K + k0 + tx] = f2bf(t[tx][i]);
}

// ---------------- bf16 GEMM: C[M,N] = A[M,K] * BT[N,K]^T ----------------
__device__ __forceinline__ void store_out(short* C, size_t idx, float v) { C[idx] = f2bf(v); }
__device__ __forceinline__ void store_out(float* C, size_t idx, float v) { C[idx] = v; }

template <typename OutT>
__global__ __launch_bounds__(256) void gemm_bt_kernel(const short* __restrict__ A,
                                                      const short* __restrict__ BT,
                                                      OutT* __restrict__ C,
                                                      int M, int N, int K) {
  __shared__ __align__(16) short As[128 * 32];
  __shared__ __align__(16) short Bs[128 * 32];
  const int tid = threadIdx.x;
  const int wid = tid >> 6;
  const int lane = tid & 63;
  const int l15 = lane & 15;
  const int l4 = lane >> 4;
  const int wr = wid >> 1;
  const int wc = wid & 1;
  const int bm = blockIdx.y * 128;
  const int bn = blockIdx.x * 128;

  f32x4 acc[4][4];
#pragma unroll
  for (int m = 0; m < 4; ++m)
#pragma unroll
    for (int n = 0; n < 4; ++n) acc[m][n] = (f32x4){0.f, 0.f, 0.f, 0.f};

  const int ebase = wid * 1024;              // 1024 bf16 elements per wave (2 x 512)
  const int e0 = ebase + lane * 8;
  const int r0 = e0 >> 5, c0 = e0 & 31;
  const int r1 = r0 + 16;                    // e0 + 512

  for (int k0 = 0; k0 < K; k0 += 32) {
    __syncthreads();
    gld_lds16(A + (size_t)(bm + r0) * K + k0 + c0, As + ebase);
    gld_lds16(A + (size_t)(bm + r1) * K + k0 + c0, As + ebase + 512);
    gld_lds16(BT + (size_t)(bn + r0) * K + k0 + c0, Bs + ebase);
    gld_lds16(BT + (size_t)(bn + r1) * K + k0 + c0, Bs + ebase + 512);
    __syncthreads();

    short8 a[4], b[4];
#pragma unroll
    for (int m = 0; m < 4; ++m)
      a[m] = *(const short8*)&As[(wr * 64 + m * 16 + l15) * 32 + l4 * 8];
#pragma unroll
    for (int n = 0; n < 4; ++n)
      b[n] = *(const short8*)&Bs[(wc * 64 + n * 16 + l15) * 32 + l4 * 8];
#pragma unroll
    for (int m = 0; m < 4; ++m)
#pragma unroll
      for (int n = 0; n < 4; ++n)
        acc[m][n] = __builtin_amdgcn_mfma_f32_16x16x32_bf16(a[m], b[n], acc[m][n], 0, 0, 0);
  }

#pragma unroll
  for (int m = 0; m < 4; ++m) {
    const int row0 = bm + wr * 64 + m * 16 + l4 * 4;
#pragma unroll
    for (int n = 0; n < 4; ++n) {
      const int col = bn + wc * 64 + n * 16 + l15;
#pragma unroll
      for (int r = 0; r < 4; ++r)
        store_out(C, (size_t)(row0 + r) * N + col, acc[m][n][r]);
    }
  }
}

// ---------------- repack V: qkv[t][2048 + h*64 + d] -> vT[h][d][t] ----------------
__global__ __launch_bounds__(256) void repack_v_kernel(const short* __restrict__ qkv,
                                                       short* __restrict__ vT) {
  const int h = blockIdx.x >> 6;
  const int t0 = (blockIdx.x & 63) << 6;
  __shared__ __align__(16) short tile[64][72];
  const int t = threadIdx.x;
  const int r = t >> 3, c = (t & 7) << 3;
#pragma unroll
  for (int i = 0; i < 2; ++i) {
    const int rr = r + i * 32;
    *(short8*)&tile[rr][c] =
        *(const short8*)&qkv[(size_t)(t0 + rr) * C3 + 2048 + h * 64 + c];
  }
  __syncthreads();
  const int d = t >> 3, tt = (t & 7) << 3;
#pragma unroll
  for (int i = 0; i < 2; ++i) {
    const int dd = d + i * 32;
    short8 v;
#pragma unroll
    for (int j = 0; j < 8; ++j) v[j] = tile[tt + j][dd];
    *(short8*)&vT[(size_t)(h * 64 + dd) * T_SEQ + t0 + tt] = v;
  }
}

// ---------------- flash attention: 32x32 MFMA, in-reg P, intra-block KV-split ----------------
// 512 blocks x 512 threads. 8 waves = 2 groups of 4; group g covers KV half g.
// Each wave: 32 q-rows (q = q0 + wg*32 + l31). End-of-kernel online-softmax merge via LDS.
__global__ __launch_bounds__(512, 4) void attn_kernel(const short* __restrict__ qkv,
                                                      const short* __restrict__ vT,
                                                      short* __restrict__ y) {
  // XCD-aware: heads {2x, 2x+1} -> XCD x (round-robin bid%8 assumption)
  const int bid = blockIdx.x;
  const int xcd = bid & 7, slot = bid >> 3;      // slot 0..63
  const int h = xcd * 2 + (slot >> 5);
  const int q0 = (slot & 31) * 128;

  const int tid = threadIdx.x;
  const int w = tid >> 6, lane = tid & 63, l31 = lane & 31, l1 = lane >> 5;
  const int g = w >> 2, wg = w & 3;
  const int kvbase = g * (T_SEQ / 2);

  __shared__ __align__(16) short Ks[2][2][4096];   // [group][dbuf][kv*64+d], d-swizzled
  __shared__ __align__(16) short Vs[2][2][4096];   // [group][dbuf][d*64+kv], kv-swizzled

  // Q B-fragments: col q = l31, k = d = ks*16 + l1*8 + j
  short8 qf[4];
  {
    const short* qp = qkv + (size_t)(q0 + wg * 32 + l31) * C3 + h * 64 + l1 * 8;
#pragma unroll
    for (int ks = 0; ks < 4; ++ks) qf[ks] = *(const short8*)(qp + ks * 16);
  }

  f32x16 oa0, oa1;   // O^T: col q=l31, row d=(r&3)+8*(r>>2)+4*l1 (+32 for oa1)
#pragma unroll
  for (int r = 0; r < 16; ++r) { oa0[r] = 0.f; oa1[r] = 0.f; }
  float m_r = -INFINITY, l_r = 0.f;
  const float SCL = 0.125f * 1.44269504f;          // 1/sqrt(64) * log2(e)
  const float TH = 8.0f / SCL;                     // defer-max threshold (p <= 2^8)

  // staging: row lr0 = wg*8 + (lane>>3) (+32 for i=1), source col pre-swizzled
  const int lr0 = wg * 8 + (lane >> 3);
  const int csw = ((lane & 7) << 3) ^ ((lane >> 3) << 3);   // shorts
  const short* kgb = qkv + 1024 + h * 64 + csw;
  const short* vgb = vT + (size_t)(h * 64 + lr0) * T_SEQ + csw;
  const int rswz = (l31 & 7) << 3;

  auto stage = [&](int buf, int kv0) {
#pragma unroll
    for (int i = 0; i < 2; ++i) {
      gld_lds16(kgb + (size_t)(kv0 + lr0 + i * 32) * C3, &Ks[g][buf][i * 2048 + wg * 512]);
      gld_lds16(vgb + (size_t)(i * 32) * T_SEQ + kv0, &Vs[g][buf][i * 2048 + wg * 512]);
    }
  };

  stage(0, kvbase);

  const int NT = T_SEQ / 2 / 64;   // 32 tiles per group
  for (int t = 0; t < NT; ++t) {
    const int cur = t & 1;
    __syncthreads();                       // drains vmcnt(0): buf[cur] ready
    if (t < NT - 1) stage(cur ^ 1, kvbase + (t + 1) * 64);

    const short* Kb = &Ks[g][cur][0];
    const short* Vb = &Vs[g][cur][0];

    // S^T = K Q^T: two 32-kv subtiles
    f32x16 s0, s1;
#pragma unroll
    for (int r = 0; r < 16; ++r) { s0[r] = 0.f; s1[r] = 0.f; }
    __builtin_amdgcn_s_setprio(1);
#pragma unroll
    for (int ks = 0; ks < 4; ++ks) {
      const int c = (ks * 16 + l1 * 8) ^ rswz;
      short8 k0 = *(const short8*)&Kb[l31 * 64 + c];
      short8 k1 = *(const short8*)&Kb[(32 + l31) * 64 + c];
      s0 = __builtin_amdgcn_mfma_f32_32x32x16_bf16(k0, qf[ks], s0, 0, 0, 0);
      s1 = __builtin_amdgcn_mfma_f32_32x32x16_bf16(k1, qf[ks], s1, 0, 0, 0);
    }
    __builtin_amdgcn_s_setprio(0);

    // online softmax, per-lane (col q = l31); tile max via depth-5 tree
    float tm;
    {
      float t8[8];
#pragma unroll
      for (int r = 0; r < 8; ++r)
        t8[r] = fmaxf(fmaxf(s0[r], s0[r + 8]), fmaxf(s1[r], s1[r + 8]));
#pragma unroll
      for (int r = 0; r < 4; ++r) t8[r] = fmaxf(t8[r], t8[r + 4]);
      tm = fmaxf(fmaxf(t8[0], t8[2]), fmaxf(t8[1], t8[3]));
    }
    tm = fmaxf(tm, __shfl_xor(tm, 32, 64));

    if (__any(tm > m_r + TH)) {            // defer-max: skip rescale on stable tiles
      const float mn = fmaxf(m_r, tm);
      const float al = exp2f((m_r - mn) * SCL);
      m_r = mn;
      l_r *= al;
#pragma unroll
      for (int r = 0; r < 16; ++r) { oa0[r] *= al; oa1[r] *= al; }
    }
    const float msc = m_r * SCL;
#pragma unroll
    for (int r = 0; r < 16; ++r) s0[r] = exp2f(fmaf(s0[r], SCL, -msc));
#pragma unroll
    for (int r = 0; r < 16; ++r) s1[r] = exp2f(fmaf(s1[r], SCL, -msc));

    // row-sum via tree
    float ps;
    {
      float u8[8];
#pragma unroll
      for (int r = 0; r < 8; ++r)
        u8[r] = (s0[r] + s0[r + 8]) + (s1[r] + s1[r + 8]);
#pragma unroll
      for (int r = 0; r < 4; ++r) u8[r] += u8[r + 4];
      ps = (u8[0] + u8[2]) + (u8[1] + u8[3]);
    }
    ps += __shfl_xor(ps, 32, 64);
    l_r += ps;

    // P -> B-fragments in-register: cvt_pk + permlane32_swap (T12)
    unsigned pw[4][4];
#pragma unroll
    for (int half = 0; half < 2; ++half) {
      const f32x16& sv = half ? s1 : s0;
#pragma unroll
      for (int kk = 0; kk < 2; ++kk) {       // local kstep within subtile
        const int ks = half * 2 + kk;
        unsigned x0 = cvt_pk_bf16(sv[kk * 8 + 0], sv[kk * 8 + 1]);
        unsigned y0 = cvt_pk_bf16(sv[kk * 8 + 4], sv[kk * 8 + 5]);
        asm volatile("v_permlane32_swap_b32 %0, %1" : "+v"(x0), "+v"(y0));
        unsigned x1 = cvt_pk_bf16(sv[kk * 8 + 2], sv[kk * 8 + 3]);
        unsigned y1 = cvt_pk_bf16(sv[kk * 8 + 6], sv[kk * 8 + 7]);
        asm volatile("v_permlane32_swap_b32 %0, %1" : "+v"(x1), "+v"(y1));
        pw[ks][0] = x0; pw[ks][1] = x1; pw[ks][2] = y0; pw[ks][3] = y1;
      }
    }

    // O^T += V^T P^T
    __builtin_amdgcn_s_setprio(1);
#pragma unroll
    for (int ks = 0; ks < 4; ++ks) {
      union { unsigned u[4]; short8 s8; } uu;
      uu.u[0] = pw[ks][0]; uu.u[1] = pw[ks][1]; uu.u[2] = pw[ks][2]; uu.u[3] = pw[ks][3];
      const int c = (ks * 16 + l1 * 8) ^ rswz;
      short8 v0 = *(const short8*)&Vb[l31 * 64 + c];
      short8 v1 = *(const short8*)&Vb[(32 + l31) * 64 + c];
      oa0 = __builtin_amdgcn_mfma_f32_32x32x16_bf16(v0, uu.s8, oa0, 0, 0, 0);
      oa1 = __builtin_amdgcn_mfma_f32_32x32x16_bf16(v1, uu.s8, oa1, 0, 0, 0);
    }
    __builtin_amdgcn_s_setprio(0);
  }

  // ---- merge the two KV halves (exact online-softmax combine), then store ----
  __syncthreads();                          // all K/V LDS use done
  float* Oex = (float*)&Vs[0][0][0];        // [r<32][slot<256], conflict-free
  float* mex = (float*)&Ks[0][0][0];        // [2][slot<256]
  const int xslot = wg * 64 + lane;         // 0..255 within group
  if (g == 1) {
#pragma unroll
    for (int r = 0; r < 16; ++r) {
      Oex[r * 256 + xslot] = oa0[r];
      Oex[(16 + r) * 256 + xslot] = oa1[r];
    }
    mex[xslot] = m_r;
    mex[256 + xslot] = l_r;
  }
  __syncthreads();
  if (g == 0) {
    const float m_b = mex[xslot], l_b = mex[256 + xslot];
    const float mm = fmaxf(m_r, m_b);
    const float a = exp2f((m_r - mm) * SCL);
    const float b = exp2f((m_b - mm) * SCL);
    const float rl = 1.0f / (l_r * a + l_b * b);
    const float ra = a * rl, rb = b * rl;
    const size_t yb = (size_t)(q0 + wg * 32 + l31) * C_DIM + h * 64;
#pragma unroll
    for (int g4 = 0; g4 < 4; ++g4) {
      short4v o0, o1;
#pragma unroll
      for (int j = 0; j < 4; ++j) {
        o0[j] = f2bf(oa0[g4 * 4 + j] * ra + Oex[(g4 * 4 + j) * 256 + xslot] * rb);
        o1[j] = f2bf(oa1[g4 * 4 + j] * ra + Oex[(16 + g4 * 4 + j) * 256 + xslot] * rb);
      }
      *(short4v*)&y[yb + g4 * 8 + l1 * 4] = o0;
      *(short4v*)&y[yb + 32 + g4 * 8 + l1 * 4] = o1;
    }
  }
}

extern "C" void kernel_launch(void* const* d_in, const int* in_sizes, int n_in,
                              void* d_out, int out_size, void* d_ws, size_t ws_size,
                              hipStream_t stream) {
  const float* x = (const float*)d_in[0];       // [T, C]
  const float* w_qkv = (const float*)d_in[1];   // [C, 3C]
  const float* w_out = (const float*)d_in[2];   // [C, C]
  float* out = (float*)d_out;                   // [T, C] fp32

  char* ws = (char*)d_ws;
  short* xb = (short*)ws;            ws += (size_t)T_SEQ * C_DIM * 2;       // 8 MB
  short* wqT = (short*)ws;           ws += (size_t)C3 * C_DIM * 2;          // 6 MB
  short* woT = (short*)ws;           ws += (size_t)C_DIM * C_DIM * 2;       // 2 MB
  short* qkv = (short*)ws;           ws += (size_t)T_SEQ * C3 * 2;          // 24 MB
  short* vT = (short*)ws;            ws += (size_t)NH * T_SEQ * HD * 2;     // 8 MB
  short* y = (short*)ws;             ws += (size_t)T_SEQ * C_DIM * 2;       // 8 MB

  // 1. convert inputs to bf16 (weights transposed to [N][K])
  conv_bf16_kernel<<<(T_SEQ * C_DIM) / (256 * 8), 256, 0, stream>>>(x, xb);
  trans_conv_kernel<<<dim3(C3 / 32, C_DIM / 32), dim3(32, 8), 0, stream>>>(w_qkv, wqT, C_DIM, C3);
  trans_conv_kernel<<<dim3(C_DIM / 32, C_DIM / 32), dim3(32, 8), 0, stream>>>(w_out, woT, C_DIM, C_DIM);

  // 2. qkv = x @ w_qkv  (bf16 out)
  gemm_bt_kernel<short><<<dim3(C3 / 128, T_SEQ / 128), 256, 0, stream>>>(xb, wqT, qkv,
                                                                         T_SEQ, C3, C_DIM);
  // 3. repack V -> V^T per head
  repack_v_kernel<<<NH * (T_SEQ / 64), 256, 0, stream>>>(qkv, vT);

  // 4. flash attention -> y [T, C] bf16
  attn_kernel<<<512, 512, 0, stream>>>(qkv, vT, y);

  // 5. out = y @ w_out  (fp32 out)
  gemm_bt_kernel<float><<<dim3(C_DIM / 128, T_SEQ / 128), 256, 0, stream>>>(y, woT, out,
                                                                            T_SEQ, C_DIM, C_DIM);
}

// Round 7
// 182.347 us; speedup vs baseline: 1.8209x; 1.1412x over previous
//
#include <hip/hip_runtime.h>
#include <hip/hip_bf16.h>

// Sizes for this problem
#define T_SEQ 4096
#define C_DIM 1024
#define NH    16
#define HD    64
#define C3    3072

typedef __attribute__((ext_vector_type(8))) short short8;
typedef __attribute__((ext_vector_type(4))) short short4v;
typedef __attribute__((ext_vector_type(4))) float f32x4;
typedef __attribute__((ext_vector_type(16))) float f32x16;

__device__ __forceinline__ short f2bf(float f) {
  union { float f; unsigned u; } v; v.f = f;
  unsigned r = v.u + 0x7FFFu + ((v.u >> 16) & 1u);   // round-to-nearest-even
  return (short)(r >> 16);
}

__device__ __forceinline__ unsigned cvt_pk_bf16(float lo, float hi) {
  unsigned r;
  asm volatile("v_cvt_pk_bf16_f32 %0, %1, %2" : "=v"(r) : "v"(lo), "v"(hi));
  return r;
}

// single-instruction 2^x (exp2f w/o fast-math is a multi-inst ocml call);
// builtin -> compiler handles TRANS-op hazards.
__device__ __forceinline__ float exp2_fast(float x) {
  return __builtin_amdgcn_exp2f(x);
}

// cross-half (lane^32) reduces. NOTE: permlane32_swap-based versions failed twice
// (suspected VALU-write->permlane-read wait-state hazard invisible inside inline asm);
// ds_bpermute-based __shfl_xor is proven correct here.
__device__ __forceinline__ float max_half64(float v) {
  return fmaxf(v, __shfl_xor(v, 32, 64));
}
__device__ __forceinline__ float sum_half64(float v) {
  return v + __shfl_xor(v, 32, 64);
}

__device__ __forceinline__ void gld_lds16(const void* g, void* l) {
  __builtin_amdgcn_global_load_lds(
      (const __attribute__((address_space(1))) unsigned int*)g,
      (__attribute__((address_space(3))) unsigned int*)l, 16, 0, 0);
}

// ---------------- fp32 -> bf16 convert (x) ----------------
__global__ __launch_bounds__(256) void conv_bf16_kernel(const float* __restrict__ in,
                                                        short* __restrict__ out) {
  const size_t i = ((size_t)blockIdx.x * 256 + threadIdx.x) * 8;
  float4 v0 = *(const float4*)(in + i);
  float4 v1 = *(const float4*)(in + i + 4);
  short8 o;
  o[0] = f2bf(v0.x); o[1] = f2bf(v0.y); o[2] = f2bf(v0.z); o[3] = f2bf(v0.w);
  o[4] = f2bf(v1.x); o[5] = f2bf(v1.y); o[6] = f2bf(v1.z); o[7] = f2bf(v1.w);
  *(short8*)(out + i) = o;
}

// ---------------- fp32 [K][N] -> bf16 [N][K] transpose-convert ----------------
__global__ void trans_conv_kernel(const float* __restrict__ in, short* __restrict__ out,
                                  int K, int N) {
  __shared__ float t[32][33];
  const int n0 = blockIdx.x * 32, k0 = blockIdx.y * 32;
  const int tx = threadIdx.x, ty = threadIdx.y;
  for (int i = ty; i < 32; i += 8) t[i][tx] = in[(size_t)(k0 + i) * N + n0 + tx];
  __syncthreads();
  for (int i = ty; i < 32; i += 8) out[(size_t)(n0 + i) * K + k0 + tx] = f2bf(t[tx][i]);
}

// ---------------- bf16 GEMM: C[M,N] = A[M,K] * BT[N,K]^T ----------------
__device__ __forceinline__ void store_out(short* C, size_t idx, float v) { C[idx] = f2bf(v); }
__device__ __forceinline__ void store_out(float* C, size_t idx, float v) { C[idx] = v; }

template <typename OutT>
__global__ __launch_bounds__(256) void gemm_bt_kernel(const short* __restrict__ A,
                                                      const short* __restrict__ BT,
                                                      OutT* __restrict__ C,
                                                      int M, int N, int K) {
  __shared__ __align__(16) short As[128 * 32];
  __shared__ __align__(16) short Bs[128 * 32];
  const int tid = threadIdx.x;
  const int wid = tid >> 6;
  const int lane = tid & 63;
  const int l15 = lane & 15;
  const int l4 = lane >> 4;
  const int wr = wid >> 1;
  const int wc = wid & 1;
  const int bm = blockIdx.y * 128;
  const int bn = blockIdx.x * 128;

  f32x4 acc[4][4];
#pragma unroll
  for (int m = 0; m < 4; ++m)
#pragma unroll
    for (int n = 0; n < 4; ++n) acc[m][n] = (f32x4){0.f, 0.f, 0.f, 0.f};

  const int ebase = wid * 1024;              // 1024 bf16 elements per wave (2 x 512)
  const int e0 = ebase + lane * 8;
  const int r0 = e0 >> 5, c0 = e0 & 31;
  const int r1 = r0 + 16;                    // e0 + 512

  for (int k0 = 0; k0 < K; k0 += 32) {
    __syncthreads();
    gld_lds16(A + (size_t)(bm + r0) * K + k0 + c0, As + ebase);
    gld_lds16(A + (size_t)(bm + r1) * K + k0 + c0, As + ebase + 512);
    gld_lds16(BT + (size_t)(bn + r0) * K + k0 + c0, Bs + ebase);
    gld_lds16(BT + (size_t)(bn + r1) * K + k0 + c0, Bs + ebase + 512);
    __syncthreads();

    short8 a[4], b[4];
#pragma unroll
    for (int m = 0; m < 4; ++m)
      a[m] = *(const short8*)&As[(wr * 64 + m * 16 + l15) * 32 + l4 * 8];
#pragma unroll
    for (int n = 0; n < 4; ++n)
      b[n] = *(const short8*)&Bs[(wc * 64 + n * 16 + l15) * 32 + l4 * 8];
#pragma unroll
    for (int m = 0; m < 4; ++m)
#pragma unroll
      for (int n = 0; n < 4; ++n)
        acc[m][n] = __builtin_amdgcn_mfma_f32_16x16x32_bf16(a[m], b[n], acc[m][n], 0, 0, 0);
  }

#pragma unroll
  for (int m = 0; m < 4; ++m) {
    const int row0 = bm + wr * 64 + m * 16 + l4 * 4;
#pragma unroll
    for (int n = 0; n < 4; ++n) {
      const int col = bn + wc * 64 + n * 16 + l15;
#pragma unroll
      for (int r = 0; r < 4; ++r)
        store_out(C, (size_t)(row0 + r) * N + col, acc[m][n][r]);
    }
  }
}

// ---------------- repack V: qkv[t][2048 + h*64 + d] -> vT[h][d][t] ----------------
__global__ __launch_bounds__(256) void repack_v_kernel(const short* __restrict__ qkv,
                                                       short* __restrict__ vT) {
  const int h = blockIdx.x >> 6;
  const int t0 = (blockIdx.x & 63) << 6;
  __shared__ __align__(16) short tile[64][72];
  const int t = threadIdx.x;
  const int r = t >> 3, c = (t & 7) << 3;
#pragma unroll
  for (int i = 0; i < 2; ++i) {
    const int rr = r + i * 32;
    *(short8*)&tile[rr][c] =
        *(const short8*)&qkv[(size_t)(t0 + rr) * C3 + 2048 + h * 64 + c];
  }
  __syncthreads();
  const int d = t >> 3, tt = (t & 7) << 3;
#pragma unroll
  for (int i = 0; i < 2; ++i) {
    const int dd = d + i * 32;
    short8 v;
#pragma unroll
    for (int j = 0; j < 8; ++j) v[j] = tile[tt + j][dd];
    *(short8*)&vT[(size_t)(h * 64 + dd) * T_SEQ + t0 + tt] = v;
  }
}

// ---------------- flash attention: 32x32 MFMA, in-reg P, intra-block KV-split ----------------
// 512 blocks x 512 threads. 8 waves = 2 groups of 4; group g covers KV half g.
// Each wave: 32 q-rows (q = q0 + wg*32 + l31). End-of-kernel online-softmax merge via LDS.
__global__ __launch_bounds__(512, 4) void attn_kernel(const short* __restrict__ qkv,
                                                      const short* __restrict__ vT,
                                                      short* __restrict__ y) {
  // XCD-aware: heads {2x, 2x+1} -> XCD x (round-robin bid%8 assumption)
  const int bid = blockIdx.x;
  const int xcd = bid & 7, slot = bid >> 3;      // slot 0..63
  const int h = xcd * 2 + (slot >> 5);
  const int q0 = (slot & 31) * 128;

  const int tid = threadIdx.x;
  const int w = tid >> 6, lane = tid & 63, l31 = lane & 31, l1 = lane >> 5;
  const int g = w >> 2, wg = w & 3;
  const int kvbase = g * (T_SEQ / 2);

  __shared__ __align__(16) short Ks[2][2][4096];   // [group][dbuf][kv*64+d], d-swizzled
  __shared__ __align__(16) short Vs[2][2][4096];   // [group][dbuf][d*64+kv], kv-swizzled

  // Q B-fragments: col q = l31, k = d = ks*16 + l1*8 + j
  short8 qf[4];
  {
    const short* qp = qkv + (size_t)(q0 + wg * 32 + l31) * C3 + h * 64 + l1 * 8;
#pragma unroll
    for (int ks = 0; ks < 4; ++ks) qf[ks] = *(const short8*)(qp + ks * 16);
  }

  f32x16 oa0, oa1;   // O^T: col q=l31, row d=(r&3)+8*(r>>2)+4*l1 (+32 for oa1)
#pragma unroll
  for (int r = 0; r < 16; ++r) { oa0[r] = 0.f; oa1[r] = 0.f; }
  float m_r = -INFINITY, l_r = 0.f;
  const float SCL = 0.125f * 1.44269504f;          // 1/sqrt(64) * log2(e)
  const float TH = 8.0f / SCL;                     // defer-max threshold (p <= 2^8)

  // staging: row lr0 = wg*8 + (lane>>3) (+32 for i=1), source col pre-swizzled
  const int lr0 = wg * 8 + (lane >> 3);
  const int csw = ((lane & 7) << 3) ^ ((lane >> 3) << 3);   // shorts
  const short* kgb = qkv + 1024 + h * 64 + csw;
  const short* vgb = vT + (size_t)(h * 64 + lr0) * T_SEQ + csw;
  const int rswz = (l31 & 7) << 3;

  auto stage = [&](int buf, int kv0) {
#pragma unroll
    for (int i = 0; i < 2; ++i) {
      gld_lds16(kgb + (size_t)(kv0 + lr0 + i * 32) * C3, &Ks[g][buf][i * 2048 + wg * 512]);
      gld_lds16(vgb + (size_t)(i * 32) * T_SEQ + kv0, &Vs[g][buf][i * 2048 + wg * 512]);
    }
  };

  stage(0, kvbase);

  const int NT = T_SEQ / 2 / 64;   // 32 tiles per group
  for (int t = 0; t < NT; ++t) {
    const int cur = t & 1;
    __syncthreads();                       // drains vmcnt(0): buf[cur] ready
    if (t < NT - 1) stage(cur ^ 1, kvbase + (t + 1) * 64);

    const short* Kb = &Ks[g][cur][0];
    const short* Vb = &Vs[g][cur][0];

    // S^T = K Q^T: two 32-kv subtiles
    f32x16 s0, s1;
#pragma unroll
    for (int r = 0; r < 16; ++r) { s0[r] = 0.f; s1[r] = 0.f; }
    __builtin_amdgcn_s_setprio(1);
#pragma unroll
    for (int ks = 0; ks < 4; ++ks) {
      const int c = (ks * 16 + l1 * 8) ^ rswz;
      short8 k0 = *(const short8*)&Kb[l31 * 64 + c];
      short8 k1 = *(const short8*)&Kb[(32 + l31) * 64 + c];
      s0 = __builtin_amdgcn_mfma_f32_32x32x16_bf16(k0, qf[ks], s0, 0, 0, 0);
      s1 = __builtin_amdgcn_mfma_f32_32x32x16_bf16(k1, qf[ks], s1, 0, 0, 0);
    }
    __builtin_amdgcn_s_setprio(0);

    // online softmax, per-lane (col q = l31); tile max via depth-5 tree
    float tm;
    {
      float t8[8];
#pragma unroll
      for (int r = 0; r < 8; ++r)
        t8[r] = fmaxf(fmaxf(s0[r], s0[r + 8]), fmaxf(s1[r], s1[r + 8]));
#pragma unroll
      for (int r = 0; r < 4; ++r) t8[r] = fmaxf(t8[r], t8[r + 4]);
      tm = fmaxf(fmaxf(t8[0], t8[2]), fmaxf(t8[1], t8[3]));
    }
    tm = max_half64(tm);

    if (__any(tm > m_r + TH)) {            // defer-max: skip rescale on stable tiles
      const float mn = fmaxf(m_r, tm);
      const float al = exp2_fast((m_r - mn) * SCL);
      m_r = mn;
      l_r *= al;
#pragma unroll
      for (int r = 0; r < 16; ++r) { oa0[r] *= al; oa1[r] *= al; }
    }
    const float msc = m_r * SCL;
#pragma unroll
    for (int r = 0; r < 16; ++r) s0[r] = exp2_fast(fmaf(s0[r], SCL, -msc));
#pragma unroll
    for (int r = 0; r < 16; ++r) s1[r] = exp2_fast(fmaf(s1[r], SCL, -msc));

    // row-sum via tree
    float ps;
    {
      float u8[8];
#pragma unroll
      for (int r = 0; r < 8; ++r)
        u8[r] = (s0[r] + s0[r + 8]) + (s1[r] + s1[r + 8]);
#pragma unroll
      for (int r = 0; r < 4; ++r) u8[r] += u8[r + 4];
      ps = (u8[0] + u8[2]) + (u8[1] + u8[3]);
    }
    ps = sum_half64(ps);
    l_r += ps;

    // P -> B-fragments in-register: cvt_pk + permlane32_swap (T12).
    // s_nop guards the VALU-write->permlane-read wait-state hazard (opaque to compiler).
    unsigned pw[4][4];
#pragma unroll
    for (int half = 0; half < 2; ++half) {
      const f32x16& sv = half ? s1 : s0;
#pragma unroll
      for (int kk = 0; kk < 2; ++kk) {       // local kstep within subtile
        const int ks = half * 2 + kk;
        unsigned x0 = cvt_pk_bf16(sv[kk * 8 + 0], sv[kk * 8 + 1]);
        unsigned y0 = cvt_pk_bf16(sv[kk * 8 + 4], sv[kk * 8 + 5]);
        asm volatile("s_nop 0\n\tv_permlane32_swap_b32 %0, %1" : "+v"(x0), "+v"(y0));
        unsigned x1 = cvt_pk_bf16(sv[kk * 8 + 2], sv[kk * 8 + 3]);
        unsigned y1 = cvt_pk_bf16(sv[kk * 8 + 6], sv[kk * 8 + 7]);
        asm volatile("s_nop 0\n\tv_permlane32_swap_b32 %0, %1" : "+v"(x1), "+v"(y1));
        pw[ks][0] = x0; pw[ks][1] = x1; pw[ks][2] = y0; pw[ks][3] = y1;
      }
    }

    // O^T += V^T P^T
    __builtin_amdgcn_s_setprio(1);
#pragma unroll
    for (int ks = 0; ks < 4; ++ks) {
      union { unsigned u[4]; short8 s8; } uu;
      uu.u[0] = pw[ks][0]; uu.u[1] = pw[ks][1]; uu.u[2] = pw[ks][2]; uu.u[3] = pw[ks][3];
      const int c = (ks * 16 + l1 * 8) ^ rswz;
      short8 v0 = *(const short8*)&Vb[l31 * 64 + c];
      short8 v1 = *(const short8*)&Vb[(32 + l31) * 64 + c];
      oa0 = __builtin_amdgcn_mfma_f32_32x32x16_bf16(v0, uu.s8, oa0, 0, 0, 0);
      oa1 = __builtin_amdgcn_mfma_f32_32x32x16_bf16(v1, uu.s8, oa1, 0, 0, 0);
    }
    __builtin_amdgcn_s_setprio(0);
  }

  // ---- merge the two KV halves (exact online-softmax combine), then store ----
  __syncthreads();                          // all K/V LDS use done
  float* Oex = (float*)&Vs[0][0][0];        // [r<32][slot<256], conflict-free
  float* mex = (float*)&Ks[0][0][0];        // [2][slot<256]
  const int xslot = wg * 64 + lane;         // 0..255 within group
  if (g == 1) {
#pragma unroll
    for (int r = 0; r < 16; ++r) {
      Oex[r * 256 + xslot] = oa0[r];
      Oex[(16 + r) * 256 + xslot] = oa1[r];
    }
    mex[xslot] = m_r;
    mex[256 + xslot] = l_r;
  }
  __syncthreads();
  if (g == 0) {
    const float m_b = mex[xslot], l_b = mex[256 + xslot];
    const float mm = fmaxf(m_r, m_b);
    const float a = exp2_fast((m_r - mm) * SCL);
    const float b = exp2_fast((m_b - mm) * SCL);
    const float rl = 1.0f / (l_r * a + l_b * b);
    const float ra = a * rl, rb = b * rl;
    const size_t yb = (size_t)(q0 + wg * 32 + l31) * C_DIM + h * 64;
#pragma unroll
    for (int g4 = 0; g4 < 4; ++g4) {
      short4v o0, o1;
#pragma unroll
      for (int j = 0; j < 4; ++j) {
        o0[j] = f2bf(oa0[g4 * 4 + j] * ra + Oex[(g4 * 4 + j) * 256 + xslot] * rb);
        o1[j] = f2bf(oa1[g4 * 4 + j] * ra + Oex[(16 + g4 * 4 + j) * 256 + xslot] * rb);
      }
      *(short4v*)&y[yb + g4 * 8 + l1 * 4] = o0;
      *(short4v*)&y[yb + 32 + g4 * 8 + l1 * 4] = o1;
    }
  }
}

extern "C" void kernel_launch(void* const* d_in, const int* in_sizes, int n_in,
                              void* d_out, int out_size, void* d_ws, size_t ws_size,
                              hipStream_t stream) {
  const float* x = (const float*)d_in[0];       // [T, C]
  const float* w_qkv = (const float*)d_in[1];   // [C, 3C]
  const float* w_out = (const float*)d_in[2];   // [C, C]
  float* out = (float*)d_out;                   // [T, C] fp32

  char* ws = (char*)d_ws;
  short* xb = (short*)ws;            ws += (size_t)T_SEQ * C_DIM * 2;       // 8 MB
  short* wqT = (short*)ws;           ws += (size_t)C3 * C_DIM * 2;          // 6 MB
  short* woT = (short*)ws;           ws += (size_t)C_DIM * C_DIM * 2;       // 2 MB
  short* qkv = (short*)ws;           ws += (size_t)T_SEQ * C3 * 2;          // 24 MB
  short* vT = (short*)ws;            ws += (size_t)NH * T_SEQ * HD * 2;     // 8 MB
  short* y = (short*)ws;             ws += (size_t)T_SEQ * C_DIM * 2;       // 8 MB

  // 1. convert inputs to bf16 (weights transposed to [N][K])
  conv_bf16_kernel<<<(T_SEQ * C_DIM) / (256 * 8), 256, 0, stream>>>(x, xb);
  trans_conv_kernel<<<dim3(C3 / 32, C_DIM / 32), dim3(32, 8), 0, stream>>>(w_qkv, wqT, C_DIM, C3);
  trans_conv_kernel<<<dim3(C_DIM / 32, C_DIM / 32), dim3(32, 8), 0, stream>>>(w_out, woT, C_DIM, C_DIM);

  // 2. qkv = x @ w_qkv  (bf16 out)
  gemm_bt_kernel<short><<<dim3(C3 / 128, T_SEQ / 128), 256, 0, stream>>>(xb, wqT, qkv,
                                                                         T_SEQ, C3, C_DIM);
  // 3. repack V -> V^T per head
  repack_v_kernel<<<NH * (T_SEQ / 64), 256, 0, stream>>>(qkv, vT);

  // 4. flash attention -> y [T, C] bf16
  attn_kernel<<<512, 512, 0, stream>>>(qkv, vT, y);

  // 5. out = y @ w_out  (fp32 out)
  gemm_bt_kernel<float><<<dim3(C_DIM / 128, T_SEQ / 128), 256, 0, stream>>>(y, woT, out,
                                                                            T_SEQ, C_DIM, C_DIM);
}

// Round 8
// 179.952 us; speedup vs baseline: 1.8451x; 1.0133x over previous
//
#include <hip/hip_runtime.h>
#include <hip/hip_bf16.h>

// Sizes for this problem
#define T_SEQ 4096
#define C_DIM 1024
#define NH    16
#define HD    64
#define C3    3072

typedef __attribute__((ext_vector_type(8))) short short8;
typedef __attribute__((ext_vector_type(4))) short short4v;
typedef __attribute__((ext_vector_type(4))) float f32x4;
typedef __attribute__((ext_vector_type(16))) float f32x16;

__device__ __forceinline__ short f2bf(float f) {
  union { float f; unsigned u; } v; v.f = f;
  unsigned r = v.u + 0x7FFFu + ((v.u >> 16) & 1u);   // round-to-nearest-even
  return (short)(r >> 16);
}

__device__ __forceinline__ unsigned cvt_pk_bf16(float lo, float hi) {
  unsigned r;
  asm volatile("v_cvt_pk_bf16_f32 %0, %1, %2" : "=v"(r) : "v"(lo), "v"(hi));
  return r;
}

// single-instruction 2^x (exp2f w/o fast-math is a multi-inst ocml call)
__device__ __forceinline__ float exp2_fast(float x) {
  return __builtin_amdgcn_exp2f(x);
}

// cross-half (lane^32) reduces via ds_bpermute-based shfl (proven correct here;
// permlane32_swap-based reduce failed twice — suspected wait-state hazard).
__device__ __forceinline__ float max_half64(float v) {
  return fmaxf(v, __shfl_xor(v, 32, 64));
}
__device__ __forceinline__ float sum_half64(float v) {
  return v + __shfl_xor(v, 32, 64);
}

__device__ __forceinline__ float m3(float a, float b, float c) {
  return fmaxf(fmaxf(a, b), c);   // clang fuses to v_max3_f32
}

__device__ __forceinline__ void gld_lds16(const void* g, void* l) {
  __builtin_amdgcn_global_load_lds(
      (const __attribute__((address_space(1))) unsigned int*)g,
      (__attribute__((address_space(3))) unsigned int*)l, 16, 0, 0);
}

// ---------------- fp32 -> bf16 convert (x) ----------------
__global__ __launch_bounds__(256) void conv_bf16_kernel(const float* __restrict__ in,
                                                        short* __restrict__ out) {
  const size_t i = ((size_t)blockIdx.x * 256 + threadIdx.x) * 8;
  float4 v0 = *(const float4*)(in + i);
  float4 v1 = *(const float4*)(in + i + 4);
  short8 o;
  o[0] = f2bf(v0.x); o[1] = f2bf(v0.y); o[2] = f2bf(v0.z); o[3] = f2bf(v0.w);
  o[4] = f2bf(v1.x); o[5] = f2bf(v1.y); o[6] = f2bf(v1.z); o[7] = f2bf(v1.w);
  *(short8*)(out + i) = o;
}

// ---------------- fp32 [K][N] -> bf16 [N][K] transpose-convert ----------------
__global__ void trans_conv_kernel(const float* __restrict__ in, short* __restrict__ out,
                                  int K, int N) {
  __shared__ float t[32][33];
  const int n0 = blockIdx.x * 32, k0 = blockIdx.y * 32;
  const int tx = threadIdx.x, ty = threadIdx.y;
  for (int i = ty; i < 32; i += 8) t[i][tx] = in[(size_t)(k0 + i) * N + n0 + tx];
  __syncthreads();
  for (int i = ty; i < 32; i += 8) out[(size_t)(n0 + i) * K + k0 + tx] = f2bf(t[tx][i]);
}

// ---------------- bf16 GEMM: C[M,N] = A[M,K] * BT[N,K]^T ----------------
__device__ __forceinline__ void store_out(short* C, size_t idx, float v) { C[idx] = f2bf(v); }
__device__ __forceinline__ void store_out(float* C, size_t idx, float v) { C[idx] = v; }

template <typename OutT>
__global__ __launch_bounds__(256) void gemm_bt_kernel(const short* __restrict__ A,
                                                      const short* __restrict__ BT,
                                                      OutT* __restrict__ C,
                                                      int M, int N, int K) {
  __shared__ __align__(16) short As[128 * 32];
  __shared__ __align__(16) short Bs[128 * 32];
  const int tid = threadIdx.x;
  const int wid = tid >> 6;
  const int lane = tid & 63;
  const int l15 = lane & 15;
  const int l4 = lane >> 4;
  const int wr = wid >> 1;
  const int wc = wid & 1;
  const int bm = blockIdx.y * 128;
  const int bn = blockIdx.x * 128;

  f32x4 acc[4][4];
#pragma unroll
  for (int m = 0; m < 4; ++m)
#pragma unroll
    for (int n = 0; n < 4; ++n) acc[m][n] = (f32x4){0.f, 0.f, 0.f, 0.f};

  const int ebase = wid * 1024;              // 1024 bf16 elements per wave (2 x 512)
  const int e0 = ebase + lane * 8;
  const int r0 = e0 >> 5, c0 = e0 & 31;
  const int r1 = r0 + 16;                    // e0 + 512

  for (int k0 = 0; k0 < K; k0 += 32) {
    __syncthreads();
    gld_lds16(A + (size_t)(bm + r0) * K + k0 + c0, As + ebase);
    gld_lds16(A + (size_t)(bm + r1) * K + k0 + c0, As + ebase + 512);
    gld_lds16(BT + (size_t)(bn + r0) * K + k0 + c0, Bs + ebase);
    gld_lds16(BT + (size_t)(bn + r1) * K + k0 + c0, Bs + ebase + 512);
    __syncthreads();

    short8 a[4], b[4];
#pragma unroll
    for (int m = 0; m < 4; ++m)
      a[m] = *(const short8*)&As[(wr * 64 + m * 16 + l15) * 32 + l4 * 8];
#pragma unroll
    for (int n = 0; n < 4; ++n)
      b[n] = *(const short8*)&Bs[(wc * 64 + n * 16 + l15) * 32 + l4 * 8];
#pragma unroll
    for (int m = 0; m < 4; ++m)
#pragma unroll
      for (int n = 0; n < 4; ++n)
        acc[m][n] = __builtin_amdgcn_mfma_f32_16x16x32_bf16(a[m], b[n], acc[m][n], 0, 0, 0);
  }

#pragma unroll
  for (int m = 0; m < 4; ++m) {
    const int row0 = bm + wr * 64 + m * 16 + l4 * 4;
#pragma unroll
    for (int n = 0; n < 4; ++n) {
      const int col = bn + wc * 64 + n * 16 + l15;
#pragma unroll
      for (int r = 0; r < 4; ++r)
        store_out(C, (size_t)(row0 + r) * N + col, acc[m][n][r]);
    }
  }
}

// ---------------- repack V: qkv[t][2048 + h*64 + d] -> vT[h][d][t] ----------------
__global__ __launch_bounds__(256) void repack_v_kernel(const short* __restrict__ qkv,
                                                       short* __restrict__ vT) {
  const int h = blockIdx.x >> 6;
  const int t0 = (blockIdx.x & 63) << 6;
  __shared__ __align__(16) short tile[64][72];
  const int t = threadIdx.x;
  const int r = t >> 3, c = (t & 7) << 3;
#pragma unroll
  for (int i = 0; i < 2; ++i) {
    const int rr = r + i * 32;
    *(short8*)&tile[rr][c] =
        *(const short8*)&qkv[(size_t)(t0 + rr) * C3 + 2048 + h * 64 + c];
  }
  __syncthreads();
  const int d = t >> 3, tt = (t & 7) << 3;
#pragma unroll
  for (int i = 0; i < 2; ++i) {
    const int dd = d + i * 32;
    short8 v;
#pragma unroll
    for (int j = 0; j < 8; ++j) v[j] = tile[tt + j][dd];
    *(short8*)&vT[(size_t)(h * 64 + dd) * T_SEQ + t0 + tt] = v;
  }
}

// ---------------- flash attention: 32x32 MFMA, in-reg P, KV-split, counted-vmcnt ----------------
// 512 blocks x 512 threads. 8 waves = 2 groups of 4; group g covers KV half g.
// Counted pipeline per tile: barrier -> stage(t+1) -> vmcnt(4) -> barrier -> compute(t).
__global__ __launch_bounds__(512, 4) void attn_kernel(const short* __restrict__ qkv,
                                                      const short* __restrict__ vT,
                                                      short* __restrict__ y) {
  // XCD-aware: heads {2x, 2x+1} -> XCD x (round-robin bid%8 assumption)
  const int bid = blockIdx.x;
  const int xcd = bid & 7, slot = bid >> 3;      // slot 0..63
  const int h = xcd * 2 + (slot >> 5);
  const int q0 = (slot & 31) * 128;

  const int tid = threadIdx.x;
  const int w = tid >> 6, lane = tid & 63, l31 = lane & 31, l1 = lane >> 5;
  const int g = w >> 2, wg = w & 3;
  const int kvbase = g * (T_SEQ / 2);

  __shared__ __align__(16) short Ks[2][2][4096];   // [group][dbuf][kv*64+d], d-swizzled
  __shared__ __align__(16) short Vs[2][2][4096];   // [group][dbuf][d*64+kv], kv-swizzled

  // Q B-fragments: col q = l31, k = d = ks*16 + l1*8 + j
  short8 qf[4];
  {
    const short* qp = qkv + (size_t)(q0 + wg * 32 + l31) * C3 + h * 64 + l1 * 8;
#pragma unroll
    for (int ks = 0; ks < 4; ++ks) qf[ks] = *(const short8*)(qp + ks * 16);
  }

  f32x16 oa0, oa1;   // O^T: col q=l31, row d=(r&3)+8*(r>>2)+4*l1 (+32 for oa1)
#pragma unroll
  for (int r = 0; r < 16; ++r) { oa0[r] = 0.f; oa1[r] = 0.f; }
  float m_r = -INFINITY, l_r = 0.f;
  const float SCL = 0.125f * 1.44269504f;          // 1/sqrt(64) * log2(e)
  const float TH = 8.0f / SCL;                     // defer-max threshold (p <= 2^8)

  // staging: row lr0 = wg*8 + (lane>>3) (+32 for i=1), source col pre-swizzled.
  // Running pointers (strength-reduced): advance by constants per tile.
  const int lr0 = wg * 8 + (lane >> 3);
  const int csw = ((lane & 7) << 3) ^ ((lane >> 3) << 3);   // shorts
  const short* kpt = qkv + 1024 + h * 64 + csw + (size_t)(kvbase + lr0) * C3;
  const short* vpt = vT + (size_t)(h * 64 + lr0) * T_SEQ + csw + kvbase;
  const int rswz = (l31 & 7) << 3;

  auto stage = [&](int buf) {
#pragma unroll
    for (int i = 0; i < 2; ++i) {
      gld_lds16(kpt + (size_t)i * 32 * C3, &Ks[g][buf][i * 2048 + wg * 512]);
      gld_lds16(vpt + (size_t)i * 32 * T_SEQ, &Vs[g][buf][i * 2048 + wg * 512]);
    }
  };

  stage(0);
  kpt += (size_t)64 * C3;
  vpt += 64;

  const int NT = T_SEQ / 2 / 64;   // 32 tiles per group
  for (int t = 0; t < NT; ++t) {
    const int cur = t & 1;
    // barrier 1: everyone done READING buf cur^1 (tile t-1) -> safe to overwrite
    __builtin_amdgcn_s_barrier();
    if (t + 1 < NT) {
      stage(cur ^ 1);
      kpt += (size_t)64 * C3;
      vpt += 64;
      asm volatile("s_waitcnt vmcnt(4)" ::: "memory");   // tile t's 4 loads landed; t+1's fly
    } else {
      asm volatile("s_waitcnt vmcnt(0)" ::: "memory");   // last tile: full drain
    }
    // barrier 2: everyone's tile-t data is in LDS
    __builtin_amdgcn_s_barrier();

    const short* Kb = &Ks[g][cur][0];
    const short* Vb = &Vs[g][cur][0];

    // S^T = K Q^T: two 32-kv subtiles
    f32x16 s0, s1;
#pragma unroll
    for (int r = 0; r < 16; ++r) { s0[r] = 0.f; s1[r] = 0.f; }
    __builtin_amdgcn_s_setprio(1);
#pragma unroll
    for (int ks = 0; ks < 4; ++ks) {
      const int c = (ks * 16 + l1 * 8) ^ rswz;
      short8 k0 = *(const short8*)&Kb[l31 * 64 + c];
      short8 k1 = *(const short8*)&Kb[(32 + l31) * 64 + c];
      s0 = __builtin_amdgcn_mfma_f32_32x32x16_bf16(k0, qf[ks], s0, 0, 0, 0);
      s1 = __builtin_amdgcn_mfma_f32_32x32x16_bf16(k1, qf[ks], s1, 0, 0, 0);
    }
    __builtin_amdgcn_s_setprio(0);

    // tile max via max3-shaped tree (v_max3_f32)
    float tm;
    {
      float v0 = m3(s0[0], s0[1], s0[2]);
      float v1 = m3(s0[3], s0[4], s0[5]);
      float v2 = m3(s0[6], s0[7], s0[8]);
      float v3 = m3(s0[9], s0[10], s0[11]);
      float v4 = m3(s0[12], s0[13], s0[14]);
      float v5 = fmaxf(s0[15], s1[0]);
      float v6 = m3(s1[1], s1[2], s1[3]);
      float v7 = m3(s1[4], s1[5], s1[6]);
      float v8 = m3(s1[7], s1[8], s1[9]);
      float v9 = m3(s1[10], s1[11], s1[12]);
      float v10 = m3(s1[13], s1[14], s1[15]);
      float w0 = m3(v0, v1, v2);
      float w1 = m3(v3, v4, v5);
      float w2 = m3(v6, v7, v8);
      float w3 = fmaxf(v9, v10);
      tm = fmaxf(m3(w0, w1, w2), w3);
    }
    tm = max_half64(tm);

    if (__any(tm > m_r + TH)) {            // defer-max: skip rescale on stable tiles
      const float mn = fmaxf(m_r, tm);
      const float al = exp2_fast((m_r - mn) * SCL);
      m_r = mn;
      l_r *= al;
#pragma unroll
      for (int r = 0; r < 16; ++r) { oa0[r] *= al; oa1[r] *= al; }
    }
    const float msc = m_r * SCL;
#pragma unroll
    for (int r = 0; r < 16; ++r) s0[r] = exp2_fast(fmaf(s0[r], SCL, -msc));
#pragma unroll
    for (int r = 0; r < 16; ++r) s1[r] = exp2_fast(fmaf(s1[r], SCL, -msc));

    // row-sum via tree
    float ps;
    {
      float u8[8];
#pragma unroll
      for (int r = 0; r < 8; ++r)
        u8[r] = (s0[r] + s0[r + 8]) + (s1[r] + s1[r + 8]);
#pragma unroll
      for (int r = 0; r < 4; ++r) u8[r] += u8[r + 4];
      ps = (u8[0] + u8[2]) + (u8[1] + u8[3]);
    }
    ps = sum_half64(ps);
    l_r += ps;

    // P -> B-fragments in-register: cvt_pk + permlane32_swap (T12).
    // s_nop guards the VALU-write->permlane-read wait-state hazard (opaque to compiler).
    unsigned pw[4][4];
#pragma unroll
    for (int half = 0; half < 2; ++half) {
      const f32x16& sv = half ? s1 : s0;
#pragma unroll
      for (int kk = 0; kk < 2; ++kk) {       // local kstep within subtile
        const int ks = half * 2 + kk;
        unsigned x0 = cvt_pk_bf16(sv[kk * 8 + 0], sv[kk * 8 + 1]);
        unsigned y0 = cvt_pk_bf16(sv[kk * 8 + 4], sv[kk * 8 + 5]);
        asm volatile("s_nop 0\n\tv_permlane32_swap_b32 %0, %1" : "+v"(x0), "+v"(y0));
        unsigned x1 = cvt_pk_bf16(sv[kk * 8 + 2], sv[kk * 8 + 3]);
        unsigned y1 = cvt_pk_bf16(sv[kk * 8 + 6], sv[kk * 8 + 7]);
        asm volatile("s_nop 0\n\tv_permlane32_swap_b32 %0, %1" : "+v"(x1), "+v"(y1));
        pw[ks][0] = x0; pw[ks][1] = x1; pw[ks][2] = y0; pw[ks][3] = y1;
      }
    }

    // O^T += V^T P^T
    __builtin_amdgcn_s_setprio(1);
#pragma unroll
    for (int ks = 0; ks < 4; ++ks) {
      union { unsigned u[4]; short8 s8; } uu;
      uu.u[0] = pw[ks][0]; uu.u[1] = pw[ks][1]; uu.u[2] = pw[ks][2]; uu.u[3] = pw[ks][3];
      const int c = (ks * 16 + l1 * 8) ^ rswz;
      short8 v0 = *(const short8*)&Vb[l31 * 64 + c];
      short8 v1 = *(const short8*)&Vb[(32 + l31) * 64 + c];
      oa0 = __builtin_amdgcn_mfma_f32_32x32x16_bf16(v0, uu.s8, oa0, 0, 0, 0);
      oa1 = __builtin_amdgcn_mfma_f32_32x32x16_bf16(v1, uu.s8, oa1, 0, 0, 0);
    }
    __builtin_amdgcn_s_setprio(0);
  }

  // ---- merge the two KV halves (exact online-softmax combine), then store ----
  __syncthreads();                          // all K/V LDS use done (full drain OK here)
  float* Oex = (float*)&Vs[0][0][0];        // [r<32][slot<256], conflict-free
  float* mex = (float*)&Ks[0][0][0];        // [2][slot<256]
  const int xslot = wg * 64 + lane;         // 0..255 within group
  if (g == 1) {
#pragma unroll
    for (int r = 0; r < 16; ++r) {
      Oex[r * 256 + xslot] = oa0[r];
      Oex[(16 + r) * 256 + xslot] = oa1[r];
    }
    mex[xslot] = m_r;
    mex[256 + xslot] = l_r;
  }
  __syncthreads();
  if (g == 0) {
    const float m_b = mex[xslot], l_b = mex[256 + xslot];
    const float mm = fmaxf(m_r, m_b);
    const float a = exp2_fast((m_r - mm) * SCL);
    const float b = exp2_fast((m_b - mm) * SCL);
    const float rl = 1.0f / (l_r * a + l_b * b);
    const float ra = a * rl, rb = b * rl;
    const size_t yb = (size_t)(q0 + wg * 32 + l31) * C_DIM + h * 64;
#pragma unroll
    for (int g4 = 0; g4 < 4; ++g4) {
      short4v o0, o1;
#pragma unroll
      for (int j = 0; j < 4; ++j) {
        o0[j] = f2bf(oa0[g4 * 4 + j] * ra + Oex[(g4 * 4 + j) * 256 + xslot] * rb);
        o1[j] = f2bf(oa1[g4 * 4 + j] * ra + Oex[(16 + g4 * 4 + j) * 256 + xslot] * rb);
      }
      *(short4v*)&y[yb + g4 * 8 + l1 * 4] = o0;
      *(short4v*)&y[yb + 32 + g4 * 8 + l1 * 4] = o1;
    }
  }
}

extern "C" void kernel_launch(void* const* d_in, const int* in_sizes, int n_in,
                              void* d_out, int out_size, void* d_ws, size_t ws_size,
                              hipStream_t stream) {
  const float* x = (const float*)d_in[0];       // [T, C]
  const float* w_qkv = (const float*)d_in[1];   // [C, 3C]
  const float* w_out = (const float*)d_in[2];   // [C, C]
  float* out = (float*)d_out;                   // [T, C] fp32

  char* ws = (char*)d_ws;
  short* xb = (short*)ws;            ws += (size_t)T_SEQ * C_DIM * 2;       // 8 MB
  short* wqT = (short*)ws;           ws += (size_t)C3 * C_DIM * 2;          // 6 MB
  short* woT = (short*)ws;           ws += (size_t)C_DIM * C_DIM * 2;       // 2 MB
  short* qkv = (short*)ws;           ws += (size_t)T_SEQ * C3 * 2;          // 24 MB
  short* vT = (short*)ws;            ws += (size_t)NH * T_SEQ * HD * 2;     // 8 MB
  short* y = (short*)ws;             ws += (size_t)T_SEQ * C_DIM * 2;       // 8 MB

  // 1. convert inputs to bf16 (weights transposed to [N][K])
  conv_bf16_kernel<<<(T_SEQ * C_DIM) / (256 * 8), 256, 0, stream>>>(x, xb);
  trans_conv_kernel<<<dim3(C3 / 32, C_DIM / 32), dim3(32, 8), 0, stream>>>(w_qkv, wqT, C_DIM, C3);
  trans_conv_kernel<<<dim3(C_DIM / 32, C_DIM / 32), dim3(32, 8), 0, stream>>>(w_out, woT, C_DIM, C_DIM);

  // 2. qkv = x @ w_qkv  (bf16 out)
  gemm_bt_kernel<short><<<dim3(C3 / 128, T_SEQ / 128), 256, 0, stream>>>(xb, wqT, qkv,
                                                                         T_SEQ, C3, C_DIM);
  // 3. repack V -> V^T per head
  repack_v_kernel<<<NH * (T_SEQ / 64), 256, 0, stream>>>(qkv, vT);

  // 4. flash attention -> y [T, C] bf16
  attn_kernel<<<512, 512, 0, stream>>>(qkv, vT, y);

  // 5. out = y @ w_out  (fp32 out)
  gemm_bt_kernel<float><<<dim3(C_DIM / 128, T_SEQ / 128), 256, 0, stream>>>(y, woT, out,
                                                                            T_SEQ, C_DIM, C_DIM);
}